// Round 16
// baseline (935.013 us; speedup 1.0000x reference)
//
#include <hip/hip_runtime.h>
#include <hip/hip_bf16.h>
#include <math.h>

#define NTOK 1024
#define DMODEL 512
#define NHEAD 8
#define HDIM 64
#define BATCH 8
#define NLAYER 6
#define ROWS (BATCH*NTOK)   // 8192
#define QKVSTR 1536
#define QKSTR 1024
#define LOG2E 1.44269504f

typedef __attribute__((ext_vector_type(8))) short bf16x8;
typedef __attribute__((ext_vector_type(4))) float f32x4;
typedef unsigned short ushort_t;

// ---------------- device helpers ----------------

__device__ __forceinline__ float silu_f(float x) { return x / (1.f + expf(-x)); }

__device__ __forceinline__ float gelu_tanh_f(float x) {
    float x3 = x * x * x;
    float y2 = 1.5957691216057308f * (x + 0.044715f * x3);
    float e = __builtin_amdgcn_exp2f(-y2 * LOG2E);
    return x / (1.f + e);
}

__device__ __forceinline__ unsigned short f2bf(float x) {
    __hip_bfloat16 b = __float2bfloat16(x);
    return *reinterpret_cast<unsigned short*>(&b);
}

__device__ __forceinline__ float bf2f(unsigned short u) {
    union { float f; unsigned v; } c;
    c.v = (unsigned)u << 16;
    return c.f;
}

__device__ __forceinline__ float wave_sum(float v) {
    #pragma unroll
    for (int o = 1; o < 64; o <<= 1) v += __shfl_xor(v, o);
    return v;
}

// ---------------- small kernels ----------------

__global__ __launch_bounds__(256) void init_z_kernel(const float* __restrict__ x,
                                                     const float* __restrict__ pe,
                                                     float* __restrict__ z) {
    int i = blockIdx.x * 256 + threadIdx.x;
    const int C4 = DMODEL / 4;
    int row = i / C4;
    int col4 = i - row * C4;
    int n = row & (NTOK - 1);
    float4 xv = ((const float4*)x)[i];
    float4 pv = ((const float4*)pe)[n * C4 + col4];
    float4 o;
    o.x = 2.f * xv.x + pv.x;
    o.y = 2.f * xv.y + pv.y;
    o.z = 2.f * xv.z + pv.z;
    o.w = 2.f * xv.w + pv.w;
    ((float4*)z)[i] = o;
}

__global__ void temb_kernel(const float* __restrict__ t, float* __restrict__ temb) {
    int b = blockIdx.x;
    int j = threadIdx.x;   // 128
    float f = expf(-9.210340371976184f * (float)j / 128.f);
    float a = t[b] * f;
    temb[b * 256 + j] = cosf(a);
    temb[b * 256 + 128 + j] = sinf(a);
}

__global__ void zero512(float* __restrict__ p) {
    p[blockIdx.x * 256 + threadIdx.x] = 0.f;
}

// ---------------- skinny (M=8) k-split GEMM ----------------
__global__ __launch_bounds__(256) void skinny_part(const float* __restrict__ A,
                                                   const float* __restrict__ W,
                                                   float* __restrict__ part,
                                                   int K, int N, int NL) {
    __shared__ float Als[8][128];
    const int l = blockIdx.z;
    const int n = blockIdx.x * 256 + threadIdx.x;
    const int kc = blockIdx.y;
    const int kbase = kc * 128;
    for (int i = threadIdx.x; i < 8 * 128; i += 256) {
        int b = i >> 7, k = i & 127;
        Als[b][k] = A[b * K + kbase + k];
    }
    __syncthreads();
    float acc[8] = {};
    const float* wp = W + (size_t)l * K * N + (size_t)kbase * N + n;
    for (int k = 0; k < 128; k += 4) {
        float w0 = wp[0];
        float w1 = wp[N];
        float w2 = wp[2 * N];
        float w3 = wp[3 * N];
        wp += 4 * (size_t)N;
        #pragma unroll
        for (int b = 0; b < 8; b++)
            acc[b] += Als[b][k] * w0 + Als[b][k + 1] * w1 + Als[b][k + 2] * w2 + Als[b][k + 3] * w3;
    }
    #pragma unroll
    for (int b = 0; b < 8; b++)
        part[((size_t)kc * 8 + b) * NL + (size_t)l * N + n] = acc[b];
}

template<int ACT>
__global__ __launch_bounds__(256) void skinny_reduce(const float* __restrict__ part,
                                                     const float* __restrict__ bias,
                                                     float* __restrict__ out,
                                                     int KC, int N, int NL) {
    int i = blockIdx.x * 256 + threadIdx.x;
    if (i >= 8 * NL) return;
    int b = i / NL, n = i - b * NL;
    float s = bias[n];
    for (int kc = 0; kc < KC; kc++) s += part[((size_t)kc * 8 + b) * NL + n];
    if (ACT == 1) s = silu_f(s);
    int l = n / N, nl = n - l * N;
    out[((size_t)l * 8 + b) * N + nl] = s;
}

// ---------------- weight prep: 5 transposes per layer; blockIdx.z = layer ----------------
__global__ __launch_bounds__(256) void transp_all(const float* __restrict__ Wq,
                                                  const float* __restrict__ Wk,
                                                  const float* __restrict__ Wv,
                                                  const float* __restrict__ W1,
                                                  const float* __restrict__ W2,
                                                  ushort_t* __restrict__ wqkv_t,
                                                  ushort_t* __restrict__ w1_t,
                                                  ushort_t* __restrict__ w2_t) {
    __shared__ float tile[32][33];
    const int L = blockIdx.z;
    Wq += (size_t)L * 512 * 512;
    Wk += (size_t)L * 512 * 512;
    Wv += (size_t)L * 512 * 512;
    W1 += (size_t)L * 512 * 2048;
    W2 += (size_t)L * 2048 * 512;
    wqkv_t += (size_t)L * QKVSTR * 512;
    w1_t += (size_t)L * 2048 * 512;
    w2_t += (size_t)L * 512 * 2048;
    int blk = blockIdx.x;
    const float* src; ushort_t* dst; int K, N, k0, n0;
    if (blk < 768) {
        int zz = blk >> 8, rem = blk & 255;
        k0 = (rem >> 4) * 32; n0 = (rem & 15) * 32;
        src = zz == 0 ? Wq : (zz == 1 ? Wk : Wv);
        dst = wqkv_t + zz * 512 * 512;
        K = 512; N = 512;
    } else if (blk < 1792) {
        int rem = blk - 768;
        n0 = (rem & 63) * 32; k0 = (rem >> 6) * 32;
        src = W1; dst = w1_t; K = 512; N = 2048;
    } else {
        int rem = blk - 1792;
        n0 = (rem & 15) * 32; k0 = (rem >> 4) * 32;
        src = W2; dst = w2_t; K = 2048; N = 512;
    }
    int c = threadIdx.x & 31, r8 = threadIdx.x >> 5;
    #pragma unroll
    for (int i = 0; i < 4; i++) {
        int r = r8 + i * 8;
        tile[r][c] = src[(size_t)(k0 + r) * N + n0 + c];
    }
    __syncthreads();
    #pragma unroll
    for (int i = 0; i < 4; i++) {
        int rr = r8 + i * 8;
        dst[(size_t)(n0 + rr) * K + k0 + c] = f2bf(tile[c][rr]);
    }
}

__global__ void pack_bias(const float* __restrict__ bq, const float* __restrict__ bk,
                          const float* __restrict__ bv, float* __restrict__ bqkv) {
    int idx = blockIdx.x * 256 + threadIdx.x;
    if (idx >= NLAYER * QKVSTR) return;
    int l = idx / QKVSTR, n = idx - l * QKVSTR;
    float v = (n < 512) ? bq[l * 512 + n] : (n < 1024) ? bk[l * 512 + n - 512] : bv[l * 512 + n - 1024];
    bqkv[idx] = v;
}

// ---------------- bf16 MFMA GEMM (2-phase dbuf + LDS-coalesced epilogue) ----------------
// SPLITK: blockIdx.z selects K-half; partial to Cout + z*M*N.
// VSPLIT: tiles with n0>=1024 (V part of qkv) are written TRANSPOSED to vtout
//         [bh=(b*8+h)][d][tok]; other tiles to Cout with row stride CS.
template<int ACT, int OUTBF, int QPRESCALE, int SPLITK, int VSPLIT>
__global__ __launch_bounds__(256) void mfma_gemm(const ushort_t* __restrict__ A,
                                                 const ushort_t* __restrict__ Bt,
                                                 const float* __restrict__ bias,
                                                 void* __restrict__ Cout,
                                                 ushort_t* __restrict__ vtout,
                                                 int M, int N, int K, int CS) {
    __shared__ ushort_t smem[4 * 128 * 64];   // 64KB: A0|A1|B0|B1; epilogue reuses as C[128][136]
    const int tid = threadIdx.x;
    const int lane = tid & 63, wv = tid >> 6;
    const int wm = (wv >> 1) * 64, wn = (wv & 1) * 64;
    const int lrow = lane & 15, lk = lane >> 4;
    const int m0 = blockIdx.x * 128, n0 = blockIdx.y * 128;
    const int srow = lane >> 3;
    const int qp = lane & 7;
    const int ql = qp ^ srow;

    int Keff = K;
    if (SPLITK) {
        Keff = K >> 1;
        const size_t koff = (size_t)blockIdx.z * Keff;
        A += koff;
        Bt += koff;
        Cout = (void*)((ushort_t*)Cout + (size_t)blockIdx.z * M * CS);
    }

    f32x4 acc[4][4];
    #pragma unroll
    for (int i = 0; i < 4; i++)
        #pragma unroll
        for (int j = 0; j < 4; j++) {
            f32x4 zz = {0.f, 0.f, 0.f, 0.f};
            acc[i][j] = zz;
        }

    const int nK = Keff >> 6;

    auto STAGE = [&](int p, int ks) {
        const int k0 = ks << 6;
        ushort_t* Ad = smem + p * 8192;
        ushort_t* Bd = smem + 16384 + p * 8192;
        #pragma unroll
        for (int it = 0; it < 4; it++) {
            int chunk = wv * 4 + it;
            int row = chunk * 8 + srow;
            const ushort_t* srcA = A + (size_t)(m0 + row) * K + k0 + ql * 8;
            const ushort_t* srcB = Bt + (size_t)(n0 + row) * K + k0 + ql * 8;
            __builtin_amdgcn_global_load_lds((const __attribute__((address_space(1))) void*)srcA,
                                             (__attribute__((address_space(3))) void*)(Ad + chunk * 512),
                                             16, 0, 0);
            __builtin_amdgcn_global_load_lds((const __attribute__((address_space(1))) void*)srcB,
                                             (__attribute__((address_space(3))) void*)(Bd + chunk * 512),
                                             16, 0, 0);
        }
    };

    STAGE(0, 0);
    int cur = 0;
    for (int ks = 0; ks < nK; ks++) {
        if (ks + 1 < nK) {
            STAGE(cur ^ 1, ks + 1);
            asm volatile("s_waitcnt vmcnt(8)" ::: "memory");
        } else {
            asm volatile("s_waitcnt vmcnt(0)" ::: "memory");
        }
        __builtin_amdgcn_s_barrier();
        asm volatile("" ::: "memory");

        const ushort_t* Ab = smem + cur * 8192;
        const ushort_t* Bb = smem + 16384 + cur * 8192;
        #pragma unroll
        for (int kk = 0; kk < 2; kk++) {
            bf16x8 af[4], bfr[4];
            #pragma unroll
            for (int f = 0; f < 4; f++) {
                int ar = wm + f * 16 + lrow;
                af[f] = *(const bf16x8*)(Ab + ar * 64 + (((kk * 4 + lk) ^ (ar & 7)) << 3));
                int br = wn + f * 16 + lrow;
                bfr[f] = *(const bf16x8*)(Bb + br * 64 + (((kk * 4 + lk) ^ (br & 7)) << 3));
            }
            #pragma unroll
            for (int i = 0; i < 4; i++)
                #pragma unroll
                for (int j = 0; j < 4; j++)
                    acc[i][j] = __builtin_amdgcn_mfma_f32_16x16x32_bf16(af[i], bfr[j], acc[i][j], 0, 0, 0);
        }
        asm volatile("" ::: "memory");
        __builtin_amdgcn_s_barrier();
        cur ^= 1;
    }

    if (OUTBF) {
        __syncthreads();   // drain LDS reads before overwriting smem with C
        #pragma unroll
        for (int j = 0; j < 4; j++) {
            int coll = wn + j * 16 + lrow;
            float bcol = bias[n0 + coll];
            #pragma unroll
            for (int i = 0; i < 4; i++) {
                #pragma unroll
                for (int r = 0; r < 4; r++) {
                    int rowl = wm + i * 16 + lk * 4 + r;
                    float v = acc[i][j][r] + bcol;
                    if (ACT == 1) v = gelu_tanh_f(v);
                    if (QPRESCALE && (n0 + coll) < 512) v *= 0.125f * LOG2E;
                    smem[rowl * 136 + coll] = f2bf(v);
                }
            }
        }
        __syncthreads();
        if (VSPLIT && n0 >= 1024) {
            // transposed writeout: vtout[(b*8+h)*64+d][tok]
            int col_l = tid & 127, seg = tid >> 7;
            int local = n0 + col_l - 1024;
            int hh = local >> 6, d = local & 63;
            int bb = m0 >> 10;
            int tokb = (m0 & 1023) + seg * 64;
            ushort_t* dst = vtout + (((size_t)(bb * 8 + hh) * 64 + d) << 10) + tokb;
            #pragma unroll
            for (int ch = 0; ch < 8; ch++) {
                ushort_t tmp[8];
                #pragma unroll
                for (int r = 0; r < 8; r++)
                    tmp[r] = smem[(seg * 64 + ch * 8 + r) * 136 + col_l];
                *(uint4*)(dst + ch * 8) = *(const uint4*)tmp;
            }
        } else {
            ushort_t* Co = (ushort_t*)Cout;
            #pragma unroll
            for (int pass = 0; pass < 8; pass++) {
                int rowl = pass * 16 + (tid >> 4);
                int cseg = (tid & 15) * 8;
                uint4 vv = *(const uint4*)(smem + rowl * 136 + cseg);
                *(uint4*)(Co + (size_t)(m0 + rowl) * CS + n0 + cseg) = vv;
            }
        }
    } else {
        #pragma unroll
        for (int j = 0; j < 4; j++) {
            int col = n0 + wn + j * 16 + lrow;
            float bcol = bias[col];
            #pragma unroll
            for (int i = 0; i < 4; i++)
                #pragma unroll
                for (int r = 0; r < 4; r++) {
                    int row = m0 + wm + i * 16 + lk * 4 + r;
                    float v = acc[i][j][r] + bcol;
                    if (ACT == 1) v = gelu_tanh_f(v);
                    ((float*)Cout)[(size_t)row * CS + col] = v;
                }
        }
    }
}

// ---------------- fused elementwise (wave-per-row, barrier-free) ----------------

__global__ __launch_bounds__(256) void ln_mod_kernel(const float* __restrict__ z,
                                                     const float* __restrict__ ada,
                                                     ushort_t* __restrict__ out,
                                                     int sh_off, int sc_off) {
    int lane = threadIdx.x & 63;
    int row = blockIdx.x * 4 + (threadIdx.x >> 6);
    int b = row >> 10;
    const float4* zr = (const float4*)(z + (size_t)row * DMODEL);
    float4 va = zr[lane * 2], vb = zr[lane * 2 + 1];
    float s = va.x + va.y + va.z + va.w + vb.x + vb.y + vb.z + vb.w;
    float mean = wave_sum(s) * (1.f / DMODEL);
    float d0 = va.x - mean, d1 = va.y - mean, d2 = va.z - mean, d3 = va.w - mean;
    float d4 = vb.x - mean, d5 = vb.y - mean, d6 = vb.z - mean, d7 = vb.w - mean;
    float ssq = d0*d0 + d1*d1 + d2*d2 + d3*d3 + d4*d4 + d5*d5 + d6*d6 + d7*d7;
    float rstd = rsqrtf(wave_sum(ssq) * (1.f / DMODEL) + 1e-6f);
    const float* ab = ada + b * (6 * DMODEL);
    const float4* scp = (const float4*)(ab + sc_off);
    const float4* shp = (const float4*)(ab + sh_off);
    float4 sca = scp[lane * 2], scb = scp[lane * 2 + 1];
    float4 sha = shp[lane * 2], shb = shp[lane * 2 + 1];
    uint4 pk;
    pk.x = (unsigned)f2bf(d0 * rstd * (1.f + sca.x) + sha.x) |
           ((unsigned)f2bf(d1 * rstd * (1.f + sca.y) + sha.y) << 16);
    pk.y = (unsigned)f2bf(d2 * rstd * (1.f + sca.z) + sha.z) |
           ((unsigned)f2bf(d3 * rstd * (1.f + sca.w) + sha.w) << 16);
    pk.z = (unsigned)f2bf(d4 * rstd * (1.f + scb.x) + shb.x) |
           ((unsigned)f2bf(d5 * rstd * (1.f + scb.y) + shb.y) << 16);
    pk.w = (unsigned)f2bf(d6 * rstd * (1.f + scb.z) + shb.z) |
           ((unsigned)f2bf(d7 * rstd * (1.f + scb.w) + shb.w) << 16);
    ((uint4*)(out + (size_t)row * DMODEL))[lane] = pk;
}

// TWO=1: add = partial0, add2 = partial1, abias added inside g*(...)
template<int TWO>
__global__ __launch_bounds__(256) void resid_ln_kernel(float* __restrict__ z,
                                                       const ushort_t* __restrict__ add,
                                                       const ushort_t* __restrict__ add2,
                                                       const float* __restrict__ abias,
                                                       const float* __restrict__ adaG, int g_off,
                                                       const float* __restrict__ adaLN, int sh_off, int sc_off,
                                                       ushort_t* __restrict__ out) {
    int lane = threadIdx.x & 63;
    int row = blockIdx.x * 4 + (threadIdx.x >> 6);
    int b = row >> 10;
    float4* zr = (float4*)(z + (size_t)row * DMODEL);
    float4 va = zr[lane * 2], vb = zr[lane * 2 + 1];
    uint4 a4 = ((const uint4*)(add + (size_t)row * DMODEL))[lane];
    const float4* gp = (const float4*)(adaG + b * (6 * DMODEL) + g_off);
    float4 ga = gp[lane * 2], gb = gp[lane * 2 + 1];
    const ushort_t* e = (const ushort_t*)&a4;
    float av[8];
    #pragma unroll
    for (int i = 0; i < 8; i++) av[i] = bf2f(e[i]);
    if (TWO) {
        uint4 a42 = ((const uint4*)(add2 + (size_t)row * DMODEL))[lane];
        const ushort_t* e2 = (const ushort_t*)&a42;
        float4 ba = ((const float4*)abias)[lane * 2];
        float4 bb = ((const float4*)abias)[lane * 2 + 1];
        av[0] += bf2f(e2[0]) + ba.x; av[1] += bf2f(e2[1]) + ba.y;
        av[2] += bf2f(e2[2]) + ba.z; av[3] += bf2f(e2[3]) + ba.w;
        av[4] += bf2f(e2[4]) + bb.x; av[5] += bf2f(e2[5]) + bb.y;
        av[6] += bf2f(e2[6]) + bb.z; av[7] += bf2f(e2[7]) + bb.w;
    }
    va.x += ga.x * av[0]; va.y += ga.y * av[1];
    va.z += ga.z * av[2]; va.w += ga.w * av[3];
    vb.x += gb.x * av[4]; vb.y += gb.y * av[5];
    vb.z += gb.z * av[6]; vb.w += gb.w * av[7];
    float ssq = va.x*va.x + va.y*va.y + va.z*va.z + va.w*va.w
              + vb.x*vb.x + vb.y*vb.y + vb.z*vb.z + vb.w*vb.w;
    if (lane == 0) ssq -= va.x * va.x;   // exclude time component
    float tot = wave_sum(ssq);
    if (lane == 0) va.x = sqrtf(1.f + tot);
    zr[lane * 2] = va; zr[lane * 2 + 1] = vb;
    // layernorm + modulate
    float s = va.x + va.y + va.z + va.w + vb.x + vb.y + vb.z + vb.w;
    float mean = wave_sum(s) * (1.f / DMODEL);
    float d0 = va.x - mean, d1 = va.y - mean, d2 = va.z - mean, d3 = va.w - mean;
    float d4 = vb.x - mean, d5 = vb.y - mean, d6 = vb.z - mean, d7 = vb.w - mean;
    float sq2 = d0*d0 + d1*d1 + d2*d2 + d3*d3 + d4*d4 + d5*d5 + d6*d6 + d7*d7;
    float rstd = rsqrtf(wave_sum(sq2) * (1.f / DMODEL) + 1e-6f);
    const float* ab = adaLN + b * (6 * DMODEL);
    const float4* scp = (const float4*)(ab + sc_off);
    const float4* shp = (const float4*)(ab + sh_off);
    float4 sca = scp[lane * 2], scb = scp[lane * 2 + 1];
    float4 sha = shp[lane * 2], shb = shp[lane * 2 + 1];
    uint4 pk;
    pk.x = (unsigned)f2bf(d0 * rstd * (1.f + sca.x) + sha.x) |
           ((unsigned)f2bf(d1 * rstd * (1.f + sca.y) + sha.y) << 16);
    pk.y = (unsigned)f2bf(d2 * rstd * (1.f + sca.z) + sha.z) |
           ((unsigned)f2bf(d3 * rstd * (1.f + sca.w) + sha.w) << 16);
    pk.z = (unsigned)f2bf(d4 * rstd * (1.f + scb.x) + shb.x) |
           ((unsigned)f2bf(d5 * rstd * (1.f + scb.y) + shb.y) << 16);
    pk.w = (unsigned)f2bf(d6 * rstd * (1.f + scb.z) + shb.z) |
           ((unsigned)f2bf(d7 * rstd * (1.f + scb.w) + shb.w) << 16);
    ((uint4*)(out + (size_t)row * DMODEL))[lane] = pk;
}

__global__ __launch_bounds__(256) void resid_final_kernel(const float* __restrict__ z,
                                                          const ushort_t* __restrict__ add,
                                                          const ushort_t* __restrict__ add2,
                                                          const float* __restrict__ abias,
                                                          const float* __restrict__ adaG, int g_off,
                                                          const float* __restrict__ mask,
                                                          float* __restrict__ out) {
    int lane = threadIdx.x & 63;
    int row = blockIdx.x * 4 + (threadIdx.x >> 6);
    int b = row >> 10;
    const float4* zr = (const float4*)(z + (size_t)row * DMODEL);
    float4 va = zr[lane * 2], vb = zr[lane * 2 + 1];
    uint4 a4 = ((const uint4*)(add + (size_t)row * DMODEL))[lane];
    uint4 a42 = ((const uint4*)(add2 + (size_t)row * DMODEL))[lane];
    const float4* gp = (const float4*)(adaG + b * (6 * DMODEL) + g_off);
    float4 ga = gp[lane * 2], gb = gp[lane * 2 + 1];
    const ushort_t* e = (const ushort_t*)&a4;
    const ushort_t* e2 = (const ushort_t*)&a42;
    float4 ba = ((const float4*)abias)[lane * 2];
    float4 bb = ((const float4*)abias)[lane * 2 + 1];
    va.x += ga.x * (bf2f(e[0]) + bf2f(e2[0]) + ba.x);
    va.y += ga.y * (bf2f(e[1]) + bf2f(e2[1]) + ba.y);
    va.z += ga.z * (bf2f(e[2]) + bf2f(e2[2]) + ba.z);
    va.w += ga.w * (bf2f(e[3]) + bf2f(e2[3]) + ba.w);
    vb.x += gb.x * (bf2f(e[4]) + bf2f(e2[4]) + bb.x);
    vb.y += gb.y * (bf2f(e[5]) + bf2f(e2[5]) + bb.y);
    vb.z += gb.z * (bf2f(e[6]) + bf2f(e2[6]) + bb.z);
    vb.w += gb.w * (bf2f(e[7]) + bf2f(e2[7]) + bb.w);
    float ssq = va.x*va.x + va.y*va.y + va.z*va.z + va.w*va.w
              + vb.x*vb.x + vb.y*vb.y + vb.z*vb.z + vb.w*vb.w;
    if (lane == 0) ssq -= va.x * va.x;
    float tot = wave_sum(ssq);
    if (lane == 0) va.x = sqrtf(1.f + tot);
    float m = mask[row];
    if (m == 0.f) {
        va.x = va.y = va.z = va.w = 0.f;
        vb.x = vb.y = vb.z = vb.w = 0.f;
    }
    float4* orow = (float4*)(out + (size_t)row * DMODEL);
    orow[lane * 2] = va; orow[lane * 2 + 1] = vb;
}

// ---------------- MFMA flash attention (8 waves, QBLK=128; K and V both gload_lds) ----------------
// qk: [ROWS][1024] bf16 (q|k, q pre-scaled); vT: [(b*8+h)*64+d][1024] bf16.
__global__ __launch_bounds__(512) void flash_attn_mfma(const ushort_t* __restrict__ qk,
                                                       const ushort_t* __restrict__ vT,
                                                       const float* __restrict__ mask,
                                                       ushort_t* __restrict__ ctx) {
    __shared__ ushort_t Kls[64 * 64];
    __shared__ ushort_t Vt[64 * 64];
    __shared__ ushort_t Pls[8][16 * 64];
    __shared__ float Mall[NTOK];   // whole mask row for this batch (4KB)

    const int tid = threadIdx.x;
    const int lane = tid & 63, w = tid >> 6;
    const int c = lane & 15, g = lane >> 4;
    const int bh = blockIdx.x;
    const int q0 = blockIdx.y * 128;
    const int b = bh >> 3, h = bh & 7;

    const ushort_t* qptr = qk + (size_t)(b * NTOK + q0 + w * 16 + c) * QKSTR + h * HDIM + g * 8;
    bf16x8 aq0 = *(const bf16x8*)(qptr);
    bf16x8 aq1 = *(const bf16x8*)(qptr + 32);

    const float mq = mask[b * NTOK + q0 + w * 16 + c];

    #pragma unroll
    for (int i = 0; i < 2; i++) Mall[tid + i * 512] = mask[b * NTOK + tid + i * 512];

    f32x4 o[4];
    #pragma unroll
    for (int j = 0; j < 4; j++) { f32x4 zz = {0.f,0.f,0.f,0.f}; o[j] = zz; }
    float l_run = 0.f;

    const int srow = lane >> 3, qp = lane & 7, ql = qp ^ srow;
    const ushort_t* vbase = vT + ((size_t)(bh * 64 + w * 8 + srow) << 10) + ql * 8;

    char* Pw = (char*)&Pls[w][0];
    const int cswz = (c & 7) << 4;

    for (int kt = 0; kt < NTOK / 64; kt++) {
        const int k0 = kt * 64;
        __syncthreads();
        {
            int row = w * 8 + srow;
            const ushort_t* src = qk + (size_t)(b * NTOK + k0 + row) * QKSTR + 512 + h * HDIM + ql * 8;
            __builtin_amdgcn_global_load_lds((const __attribute__((address_space(1))) void*)src,
                                             (__attribute__((address_space(3))) void*)(Kls + w * 512),
                                             16, 0, 0);
        }
        {
            const ushort_t* src = vbase + k0;
            __builtin_amdgcn_global_load_lds((const __attribute__((address_space(1))) void*)src,
                                             (__attribute__((address_space(3))) void*)(Vt + w * 512),
                                             16, 0, 0);
        }
        __syncthreads();

        f32x4 s[4];
        #pragma unroll
        for (int j = 0; j < 4; j++) { f32x4 zz = {0.f,0.f,0.f,0.f}; s[j] = zz; }
        __builtin_amdgcn_s_setprio(1);
        #pragma unroll
        for (int j = 0; j < 4; j++) {
            int row = j * 16 + c;
            bf16x8 ak0 = *(const bf16x8*)(Kls + row * 64 + ((g ^ (row & 7)) << 3));
            bf16x8 ak1 = *(const bf16x8*)(Kls + row * 64 + (((4 + g) ^ (row & 7)) << 3));
            s[j] = __builtin_amdgcn_mfma_f32_16x16x32_bf16(ak0, aq0, s[j], 0, 0, 0);
            s[j] = __builtin_amdgcn_mfma_f32_16x16x32_bf16(ak1, aq1, s[j], 0, 0, 0);
        }
        __builtin_amdgcn_s_setprio(0);

        #pragma unroll
        for (int j = 0; j < 4; j++) {
            float4 mk4 = *(const float4*)&Mall[k0 + j * 16 + 4 * g];
            const float* mkp = (const float*)&mk4;
            float p[4];
            #pragma unroll
            for (int r = 0; r < 4; r++) {
                float mm = mq * mkp[r];
                float sv = s[j][r] + (mm == 0.f ? -14427.0f : mm * LOG2E);
                p[r] = exp2f(sv);
                l_run += p[r];
            }
            uint2 pk2;
            pk2.x = (unsigned)f2bf(p[0]) | ((unsigned)f2bf(p[1]) << 16);
            pk2.y = (unsigned)f2bf(p[2]) | ((unsigned)f2bf(p[3]) << 16);
            *(uint2*)(Pw + c * 128 + ((j * 32 + g * 8) ^ cswz)) = pk2;
        }

        __builtin_amdgcn_s_setprio(1);
        #pragma unroll
        for (int kk = 0; kk < 2; kk++) {
            bf16x8 pa = *(const bf16x8*)(Pw + c * 128 + ((kk * 64 + g * 16) ^ cswz));
            #pragma unroll
            for (int j = 0; j < 4; j++) {
                int vr = j * 16 + c;
                bf16x8 bv = *(const bf16x8*)(Vt + vr * 64 + (((kk * 4 + g) ^ (vr & 7)) << 3));
                o[j] = __builtin_amdgcn_mfma_f32_16x16x32_bf16(pa, bv, o[j], 0, 0, 0);
            }
        }
        __builtin_amdgcn_s_setprio(0);
    }

    l_run += __shfl_xor(l_run, 16);
    l_run += __shfl_xor(l_run, 32);

    float invr[4];
    #pragma unroll
    for (int r = 0; r < 4; r++) invr[r] = 1.f / __shfl(l_run, (g << 4) + 4 * g + r);
    #pragma unroll
    for (int r = 0; r < 4; r++) {
        size_t row = (size_t)(b * NTOK + q0 + w * 16 + 4 * g + r) * DMODEL + h * HDIM;
        #pragma unroll
        for (int j = 0; j < 4; j++)
            ctx[row + j * 16 + c] = f2bf(o[j][r] * invr[r]);
    }
}

// ---------------- launch ----------------

extern "C" void kernel_launch(void* const* d_in, const int* in_sizes, int n_in,
                              void* d_out, int out_size, void* d_ws, size_t ws_size,
                              hipStream_t stream) {
    const float* t    = (const float*)d_in[0];
    const float* x    = (const float*)d_in[1];
    const float* mask = (const float*)d_in[2];
    const float* pe   = (const float*)d_in[3];
    const float* tw1  = (const float*)d_in[4];
    const float* tb1  = (const float*)d_in[5];
    const float* tw2  = (const float*)d_in[6];
    const float* tb2  = (const float*)d_in[7];
    const float* Wq   = (const float*)d_in[8];
    const float* bq   = (const float*)d_in[9];
    const float* Wk   = (const float*)d_in[10];
    const float* bk   = (const float*)d_in[11];
    const float* Wv   = (const float*)d_in[12];
    const float* bv   = (const float*)d_in[13];
    const float* W1   = (const float*)d_in[14];
    const float* b1   = (const float*)d_in[15];
    const float* W2   = (const float*)d_in[16];
    const float* b2   = (const float*)d_in[17];
    const float* Wada = (const float*)d_in[18];
    const float* bada = (const float*)d_in[19];
    float* out = (float*)d_out;

    const bool hoist = ws_size >= 113129472ull;
    const int WL = hoist ? NLAYER : 1;

    float* z      = (float*)d_ws;
    ushort_t* cxb = (ushort_t*)(z + (size_t)ROWS * DMODEL);       // partial0 / ctx (8.4MB)
    ushort_t* cxb2 = cxb + (size_t)ROWS * DMODEL;                 // partial1 (8.4MB)
    ushort_t* mid = cxb2 + (size_t)ROWS * DMODEL;                 // 8192x2048 (32MB)
    ushort_t* qk  = mid;                                          // q|k [ROWS][1024] (16.8MB, aliased)
    ushort_t* vT  = mid + (size_t)ROWS * QKSTR;                   // vT [64bh][64d][1024] (8.4MB, aliased)
    ushort_t* hb  = mid + (size_t)ROWS * 2048;
    ushort_t* wqkv_t = hb + (size_t)ROWS * DMODEL;
    ushort_t* w1_t   = wqkv_t + (size_t)WL * QKVSTR * 512;
    ushort_t* w2_t   = w1_t + (size_t)WL * 2048 * 512;
    float* bqkv  = (float*)(w2_t + (size_t)WL * 512 * 2048);
    float* fzero = bqkv + NLAYER * QKVSTR;
    float* temb  = fzero + 512;
    float* cmid  = temb + BATCH * 256;
    float* scs   = cmid + BATCH * DMODEL;
    float* part  = scs + BATCH * DMODEL;
    float* ada_all = part + 4 * 8 * (NLAYER * 3072);

    init_z_kernel<<<ROWS * DMODEL / 4 / 256, 256, 0, stream>>>(x, pe, z);
    temb_kernel<<<BATCH, 128, 0, stream>>>(t, temb);
    pack_bias<<<(NLAYER * QKVSTR + 255) / 256, 256, 0, stream>>>(bq, bk, bv, bqkv);
    zero512<<<2, 256, 0, stream>>>(fzero);

    skinny_part<<<dim3(2, 2, 1), 256, 0, stream>>>(temb, tw1, part, 256, 512, 512);
    skinny_reduce<1><<<16, 256, 0, stream>>>(part, tb1, cmid, 2, 512, 512);
    skinny_part<<<dim3(2, 4, 1), 256, 0, stream>>>(cmid, tw2, part, 512, 512, 512);
    skinny_reduce<1><<<16, 256, 0, stream>>>(part, tb2, scs, 4, 512, 512);
    skinny_part<<<dim3(12, 4, NLAYER), 256, 0, stream>>>(scs, Wada, part, 512, 3072, NLAYER * 3072);
    skinny_reduce<0><<<(8 * NLAYER * 3072 + 255) / 256, 256, 0, stream>>>(
        part, bada, ada_all, 4, 3072, NLAYER * 3072);

    if (hoist) {
        transp_all<<<dim3(2816, 1, NLAYER), 256, 0, stream>>>(Wq, Wk, Wv, W1, W2,
                                                              wqkv_t, w1_t, w2_t);
    }

    dim3 gqkv(ROWS / 128, QKVSTR / 128);
    dim3 gmlp1(ROWS / 128, 2048 / 128);
    dim3 gmlp2(ROWS / 128, DMODEL / 128, 2);   // split-K=2
    dim3 ga(BATCH * NHEAD, NTOK / 128);

    ln_mod_kernel<<<ROWS / 4, 256, 0, stream>>>(z, ada_all, hb, 0, 512);

    for (int i = 0; i < NLAYER; i++) {
        const float* ada = ada_all + (size_t)i * 8 * 3072;

        const ushort_t* wq_i = hoist ? wqkv_t + (size_t)i * QKVSTR * 512 : wqkv_t;
        const ushort_t* w1_i = hoist ? w1_t + (size_t)i * 2048 * 512 : w1_t;
        const ushort_t* w2_i = hoist ? w2_t + (size_t)i * 512 * 2048 : w2_t;

        if (!hoist) {
            transp_all<<<dim3(2816, 1, 1), 256, 0, stream>>>(Wq + (size_t)i * 512 * 512,
                                                             Wk + (size_t)i * 512 * 512,
                                                             Wv + (size_t)i * 512 * 512,
                                                             W1 + (size_t)i * 512 * 2048,
                                                             W2 + (size_t)i * 2048 * 512,
                                                             wqkv_t, w1_t, w2_t);
        }

        // QKV: q|k -> qk (stride 1024, q prescaled), v -> vT transposed
        mfma_gemm<0, 1, 1, 0, 1><<<gqkv, 256, 0, stream>>>(hb, wq_i, bqkv + i * QKVSTR,
                                                           qk, vT, ROWS, QKVSTR, DMODEL, QKSTR);

        flash_attn_mfma<<<ga, 512, 0, stream>>>(qk, vT, mask, cxb);

        resid_ln_kernel<0><<<ROWS / 4, 256, 0, stream>>>(z, cxb, nullptr, nullptr,
                                                         ada, 2 * DMODEL,
                                                         ada, 3 * DMODEL, 4 * DMODEL, hb);

        mfma_gemm<1, 1, 0, 0, 0><<<gmlp1, 256, 0, stream>>>(hb, w1_i, b1 + (size_t)i * 4 * DMODEL,
                                                            mid, nullptr, ROWS, 4 * DMODEL, DMODEL, 2048);
        mfma_gemm<0, 1, 0, 1, 0><<<gmlp2, 256, 0, stream>>>(mid, w2_i, fzero,
                                                            cxb, nullptr, ROWS, DMODEL, 4 * DMODEL, DMODEL);

        if (i < NLAYER - 1) {
            const float* adan = ada_all + (size_t)(i + 1) * 8 * 3072;
            resid_ln_kernel<1><<<ROWS / 4, 256, 0, stream>>>(z, cxb, cxb2, b2 + (size_t)i * DMODEL,
                                                             ada, 5 * DMODEL,
                                                             adan, 0, 512, hb);
        } else {
            resid_final_kernel<<<ROWS / 4, 256, 0, stream>>>(z, cxb, cxb2, b2 + (size_t)i * DMODEL,
                                                             ada, 5 * DMODEL, mask, out);
        }
    }
}

// Round 17
// 912.682 us; speedup vs baseline: 1.0245x; 1.0245x over previous
//
#include <hip/hip_runtime.h>
#include <hip/hip_bf16.h>
#include <math.h>

#define NTOK 1024
#define DMODEL 512
#define NHEAD 8
#define HDIM 64
#define BATCH 8
#define NLAYER 6
#define ROWS (BATCH*NTOK)   // 8192
#define QKVSTR 1536
#define LOG2E 1.44269504f

typedef __attribute__((ext_vector_type(8))) short bf16x8;
typedef __attribute__((ext_vector_type(4))) float f32x4;
typedef unsigned short ushort_t;

// ---------------- device helpers ----------------

__device__ __forceinline__ float silu_f(float x) { return x / (1.f + expf(-x)); }

__device__ __forceinline__ float gelu_tanh_f(float x) {
    float x3 = x * x * x;
    float y2 = 1.5957691216057308f * (x + 0.044715f * x3);
    float e = __builtin_amdgcn_exp2f(-y2 * LOG2E);
    return x / (1.f + e);
}

__device__ __forceinline__ unsigned short f2bf(float x) {
    __hip_bfloat16 b = __float2bfloat16(x);
    return *reinterpret_cast<unsigned short*>(&b);
}

__device__ __forceinline__ float bf2f(unsigned short u) {
    union { float f; unsigned v; } c;
    c.v = (unsigned)u << 16;
    return c.f;
}

__device__ __forceinline__ float wave_sum(float v) {
    #pragma unroll
    for (int o = 1; o < 64; o <<= 1) v += __shfl_xor(v, o);
    return v;
}

// ---------------- small kernels ----------------

__global__ __launch_bounds__(256) void init_z_kernel(const float* __restrict__ x,
                                                     const float* __restrict__ pe,
                                                     float* __restrict__ z) {
    int i = blockIdx.x * 256 + threadIdx.x;
    const int C4 = DMODEL / 4;
    int row = i / C4;
    int col4 = i - row * C4;
    int n = row & (NTOK - 1);
    float4 xv = ((const float4*)x)[i];
    float4 pv = ((const float4*)pe)[n * C4 + col4];
    float4 o;
    o.x = 2.f * xv.x + pv.x;
    o.y = 2.f * xv.y + pv.y;
    o.z = 2.f * xv.z + pv.z;
    o.w = 2.f * xv.w + pv.w;
    ((float4*)z)[i] = o;
}

__global__ void temb_kernel(const float* __restrict__ t, float* __restrict__ temb) {
    int b = blockIdx.x;
    int j = threadIdx.x;   // 128
    float f = expf(-9.210340371976184f * (float)j / 128.f);
    float a = t[b] * f;
    temb[b * 256 + j] = cosf(a);
    temb[b * 256 + 128 + j] = sinf(a);
}

__global__ void zero512(float* __restrict__ p) {
    p[blockIdx.x * 256 + threadIdx.x] = 0.f;
}

// ---------------- skinny (M=8) k-split GEMM ----------------
__global__ __launch_bounds__(256) void skinny_part(const float* __restrict__ A,
                                                   const float* __restrict__ W,
                                                   float* __restrict__ part,
                                                   int K, int N, int NL) {
    __shared__ float Als[8][128];
    const int l = blockIdx.z;
    const int n = blockIdx.x * 256 + threadIdx.x;
    const int kc = blockIdx.y;
    const int kbase = kc * 128;
    for (int i = threadIdx.x; i < 8 * 128; i += 256) {
        int b = i >> 7, k = i & 127;
        Als[b][k] = A[b * K + kbase + k];
    }
    __syncthreads();
    float acc[8] = {};
    const float* wp = W + (size_t)l * K * N + (size_t)kbase * N + n;
    for (int k = 0; k < 128; k += 4) {
        float w0 = wp[0];
        float w1 = wp[N];
        float w2 = wp[2 * N];
        float w3 = wp[3 * N];
        wp += 4 * (size_t)N;
        #pragma unroll
        for (int b = 0; b < 8; b++)
            acc[b] += Als[b][k] * w0 + Als[b][k + 1] * w1 + Als[b][k + 2] * w2 + Als[b][k + 3] * w3;
    }
    #pragma unroll
    for (int b = 0; b < 8; b++)
        part[((size_t)kc * 8 + b) * NL + (size_t)l * N + n] = acc[b];
}

template<int ACT>
__global__ __launch_bounds__(256) void skinny_reduce(const float* __restrict__ part,
                                                     const float* __restrict__ bias,
                                                     float* __restrict__ out,
                                                     int KC, int N, int NL) {
    int i = blockIdx.x * 256 + threadIdx.x;
    if (i >= 8 * NL) return;
    int b = i / NL, n = i - b * NL;
    float s = bias[n];
    for (int kc = 0; kc < KC; kc++) s += part[((size_t)kc * 8 + b) * NL + n];
    if (ACT == 1) s = silu_f(s);
    int l = n / N, nl = n - l * N;
    out[((size_t)l * 8 + b) * N + nl] = s;
}

// ---------------- weight prep: 5 transposes per layer; blockIdx.z = layer ----------------
__global__ __launch_bounds__(256) void transp_all(const float* __restrict__ Wq,
                                                  const float* __restrict__ Wk,
                                                  const float* __restrict__ Wv,
                                                  const float* __restrict__ W1,
                                                  const float* __restrict__ W2,
                                                  ushort_t* __restrict__ wqkv_t,
                                                  ushort_t* __restrict__ w1_t,
                                                  ushort_t* __restrict__ w2_t) {
    __shared__ float tile[32][33];
    const int L = blockIdx.z;
    Wq += (size_t)L * 512 * 512;
    Wk += (size_t)L * 512 * 512;
    Wv += (size_t)L * 512 * 512;
    W1 += (size_t)L * 512 * 2048;
    W2 += (size_t)L * 2048 * 512;
    wqkv_t += (size_t)L * QKVSTR * 512;
    w1_t += (size_t)L * 2048 * 512;
    w2_t += (size_t)L * 512 * 2048;
    int blk = blockIdx.x;
    const float* src; ushort_t* dst; int K, N, k0, n0;
    if (blk < 768) {
        int zz = blk >> 8, rem = blk & 255;
        k0 = (rem >> 4) * 32; n0 = (rem & 15) * 32;
        src = zz == 0 ? Wq : (zz == 1 ? Wk : Wv);
        dst = wqkv_t + zz * 512 * 512;
        K = 512; N = 512;
    } else if (blk < 1792) {
        int rem = blk - 768;
        n0 = (rem & 63) * 32; k0 = (rem >> 6) * 32;
        src = W1; dst = w1_t; K = 512; N = 2048;
    } else {
        int rem = blk - 1792;
        n0 = (rem & 15) * 32; k0 = (rem >> 4) * 32;
        src = W2; dst = w2_t; K = 2048; N = 512;
    }
    int c = threadIdx.x & 31, r8 = threadIdx.x >> 5;
    #pragma unroll
    for (int i = 0; i < 4; i++) {
        int r = r8 + i * 8;
        tile[r][c] = src[(size_t)(k0 + r) * N + n0 + c];
    }
    __syncthreads();
    #pragma unroll
    for (int i = 0; i < 4; i++) {
        int rr = r8 + i * 8;
        dst[(size_t)(n0 + rr) * K + k0 + c] = f2bf(tile[c][rr]);
    }
}

__global__ void pack_bias(const float* __restrict__ bq, const float* __restrict__ bk,
                          const float* __restrict__ bv, float* __restrict__ bqkv) {
    int idx = blockIdx.x * 256 + threadIdx.x;
    if (idx >= NLAYER * QKVSTR) return;
    int l = idx / QKVSTR, n = idx - l * QKVSTR;
    float v = (n < 512) ? bq[l * 512 + n] : (n < 1024) ? bk[l * 512 + n - 512] : bv[l * 512 + n - 1024];
    bqkv[idx] = v;
}

// ---------------- bf16 MFMA GEMM (2-phase dbuf + LDS-coalesced epilogue) ----------------
// SPLITK: blockIdx.z selects K-half; partial written to Cout + z*M*N (bf16 only)
template<int ACT, int OUTBF, int QPRESCALE, int SPLITK>
__global__ __launch_bounds__(256) void mfma_gemm(const ushort_t* __restrict__ A,
                                                 const ushort_t* __restrict__ Bt,
                                                 const float* __restrict__ bias,
                                                 void* __restrict__ Cout,
                                                 int M, int N, int K) {
    __shared__ ushort_t smem[4 * 128 * 64];   // 64KB: A0|A1|B0|B1; epilogue reuses as C[128][136]
    const int tid = threadIdx.x;
    const int lane = tid & 63, wv = tid >> 6;
    const int wm = (wv >> 1) * 64, wn = (wv & 1) * 64;
    const int lrow = lane & 15, lk = lane >> 4;
    const int m0 = blockIdx.x * 128, n0 = blockIdx.y * 128;
    const int srow = lane >> 3;
    const int qp = lane & 7;
    const int ql = qp ^ srow;

    int Keff = K;
    if (SPLITK) {
        Keff = K >> 1;
        const size_t koff = (size_t)blockIdx.z * Keff;
        A += koff;
        Bt += koff;
        Cout = (void*)((ushort_t*)Cout + (size_t)blockIdx.z * M * N);
    }

    f32x4 acc[4][4];
    #pragma unroll
    for (int i = 0; i < 4; i++)
        #pragma unroll
        for (int j = 0; j < 4; j++) {
            f32x4 zz = {0.f, 0.f, 0.f, 0.f};
            acc[i][j] = zz;
        }

    const int nK = Keff >> 6;

    auto STAGE = [&](int p, int ks) {
        const int k0 = ks << 6;
        ushort_t* Ad = smem + p * 8192;
        ushort_t* Bd = smem + 16384 + p * 8192;
        #pragma unroll
        for (int it = 0; it < 4; it++) {
            int chunk = wv * 4 + it;
            int row = chunk * 8 + srow;
            const ushort_t* srcA = A + (size_t)(m0 + row) * K + k0 + ql * 8;
            const ushort_t* srcB = Bt + (size_t)(n0 + row) * K + k0 + ql * 8;
            __builtin_amdgcn_global_load_lds((const __attribute__((address_space(1))) void*)srcA,
                                             (__attribute__((address_space(3))) void*)(Ad + chunk * 512),
                                             16, 0, 0);
            __builtin_amdgcn_global_load_lds((const __attribute__((address_space(1))) void*)srcB,
                                             (__attribute__((address_space(3))) void*)(Bd + chunk * 512),
                                             16, 0, 0);
        }
    };

    STAGE(0, 0);
    int cur = 0;
    for (int ks = 0; ks < nK; ks++) {
        if (ks + 1 < nK) {
            STAGE(cur ^ 1, ks + 1);
            asm volatile("s_waitcnt vmcnt(8)" ::: "memory");
        } else {
            asm volatile("s_waitcnt vmcnt(0)" ::: "memory");
        }
        __builtin_amdgcn_s_barrier();
        asm volatile("" ::: "memory");

        const ushort_t* Ab = smem + cur * 8192;
        const ushort_t* Bb = smem + 16384 + cur * 8192;
        #pragma unroll
        for (int kk = 0; kk < 2; kk++) {
            bf16x8 af[4], bfr[4];
            #pragma unroll
            for (int f = 0; f < 4; f++) {
                int ar = wm + f * 16 + lrow;
                af[f] = *(const bf16x8*)(Ab + ar * 64 + (((kk * 4 + lk) ^ (ar & 7)) << 3));
                int br = wn + f * 16 + lrow;
                bfr[f] = *(const bf16x8*)(Bb + br * 64 + (((kk * 4 + lk) ^ (br & 7)) << 3));
            }
            #pragma unroll
            for (int i = 0; i < 4; i++)
                #pragma unroll
                for (int j = 0; j < 4; j++)
                    acc[i][j] = __builtin_amdgcn_mfma_f32_16x16x32_bf16(af[i], bfr[j], acc[i][j], 0, 0, 0);
        }
        asm volatile("" ::: "memory");
        __builtin_amdgcn_s_barrier();
        cur ^= 1;
    }

    if (OUTBF) {
        __syncthreads();   // drain LDS reads before overwriting smem with C
        #pragma unroll
        for (int j = 0; j < 4; j++) {
            int coll = wn + j * 16 + lrow;
            float bcol = bias[n0 + coll];
            #pragma unroll
            for (int i = 0; i < 4; i++) {
                #pragma unroll
                for (int r = 0; r < 4; r++) {
                    int rowl = wm + i * 16 + lk * 4 + r;
                    float v = acc[i][j][r] + bcol;
                    if (ACT == 1) v = gelu_tanh_f(v);
                    if (QPRESCALE && (n0 + coll) < 512) v *= 0.125f * LOG2E;
                    smem[rowl * 136 + coll] = f2bf(v);
                }
            }
        }
        __syncthreads();
        ushort_t* Co = (ushort_t*)Cout;
        #pragma unroll
        for (int pass = 0; pass < 8; pass++) {
            int rowl = pass * 16 + (tid >> 4);
            int cseg = (tid & 15) * 8;
            uint4 vv = *(const uint4*)(smem + rowl * 136 + cseg);
            *(uint4*)(Co + (size_t)(m0 + rowl) * N + n0 + cseg) = vv;
        }
    } else {
        #pragma unroll
        for (int j = 0; j < 4; j++) {
            int col = n0 + wn + j * 16 + lrow;
            float bcol = bias[col];
            #pragma unroll
            for (int i = 0; i < 4; i++)
                #pragma unroll
                for (int r = 0; r < 4; r++) {
                    int row = m0 + wm + i * 16 + lk * 4 + r;
                    float v = acc[i][j][r] + bcol;
                    if (ACT == 1) v = gelu_tanh_f(v);
                    ((float*)Cout)[(size_t)row * N + col] = v;
                }
        }
    }
}

// ---------------- fused elementwise (wave-per-row, barrier-free) ----------------

__global__ __launch_bounds__(256) void ln_mod_kernel(const float* __restrict__ z,
                                                     const float* __restrict__ ada,
                                                     ushort_t* __restrict__ out,
                                                     int sh_off, int sc_off) {
    int lane = threadIdx.x & 63;
    int row = blockIdx.x * 4 + (threadIdx.x >> 6);
    int b = row >> 10;
    const float4* zr = (const float4*)(z + (size_t)row * DMODEL);
    float4 va = zr[lane * 2], vb = zr[lane * 2 + 1];
    float s = va.x + va.y + va.z + va.w + vb.x + vb.y + vb.z + vb.w;
    float mean = wave_sum(s) * (1.f / DMODEL);
    float d0 = va.x - mean, d1 = va.y - mean, d2 = va.z - mean, d3 = va.w - mean;
    float d4 = vb.x - mean, d5 = vb.y - mean, d6 = vb.z - mean, d7 = vb.w - mean;
    float ssq = d0*d0 + d1*d1 + d2*d2 + d3*d3 + d4*d4 + d5*d5 + d6*d6 + d7*d7;
    float rstd = rsqrtf(wave_sum(ssq) * (1.f / DMODEL) + 1e-6f);
    const float* ab = ada + b * (6 * DMODEL);
    const float4* scp = (const float4*)(ab + sc_off);
    const float4* shp = (const float4*)(ab + sh_off);
    float4 sca = scp[lane * 2], scb = scp[lane * 2 + 1];
    float4 sha = shp[lane * 2], shb = shp[lane * 2 + 1];
    uint4 pk;
    pk.x = (unsigned)f2bf(d0 * rstd * (1.f + sca.x) + sha.x) |
           ((unsigned)f2bf(d1 * rstd * (1.f + sca.y) + sha.y) << 16);
    pk.y = (unsigned)f2bf(d2 * rstd * (1.f + sca.z) + sha.z) |
           ((unsigned)f2bf(d3 * rstd * (1.f + sca.w) + sha.w) << 16);
    pk.z = (unsigned)f2bf(d4 * rstd * (1.f + scb.x) + shb.x) |
           ((unsigned)f2bf(d5 * rstd * (1.f + scb.y) + shb.y) << 16);
    pk.w = (unsigned)f2bf(d6 * rstd * (1.f + scb.z) + shb.z) |
           ((unsigned)f2bf(d7 * rstd * (1.f + scb.w) + shb.w) << 16);
    ((uint4*)(out + (size_t)row * DMODEL))[lane] = pk;
}

// TWO=1: add = partial0, add2 = partial1, abias added inside g*(...)
template<int TWO>
__global__ __launch_bounds__(256) void resid_ln_kernel(float* __restrict__ z,
                                                       const ushort_t* __restrict__ add,
                                                       const ushort_t* __restrict__ add2,
                                                       const float* __restrict__ abias,
                                                       const float* __restrict__ adaG, int g_off,
                                                       const float* __restrict__ adaLN, int sh_off, int sc_off,
                                                       ushort_t* __restrict__ out) {
    int lane = threadIdx.x & 63;
    int row = blockIdx.x * 4 + (threadIdx.x >> 6);
    int b = row >> 10;
    float4* zr = (float4*)(z + (size_t)row * DMODEL);
    float4 va = zr[lane * 2], vb = zr[lane * 2 + 1];
    uint4 a4 = ((const uint4*)(add + (size_t)row * DMODEL))[lane];
    const float4* gp = (const float4*)(adaG + b * (6 * DMODEL) + g_off);
    float4 ga = gp[lane * 2], gb = gp[lane * 2 + 1];
    const ushort_t* e = (const ushort_t*)&a4;
    float av[8];
    #pragma unroll
    for (int i = 0; i < 8; i++) av[i] = bf2f(e[i]);
    if (TWO) {
        uint4 a42 = ((const uint4*)(add2 + (size_t)row * DMODEL))[lane];
        const ushort_t* e2 = (const ushort_t*)&a42;
        float4 ba = ((const float4*)abias)[lane * 2];
        float4 bb = ((const float4*)abias)[lane * 2 + 1];
        av[0] += bf2f(e2[0]) + ba.x; av[1] += bf2f(e2[1]) + ba.y;
        av[2] += bf2f(e2[2]) + ba.z; av[3] += bf2f(e2[3]) + ba.w;
        av[4] += bf2f(e2[4]) + bb.x; av[5] += bf2f(e2[5]) + bb.y;
        av[6] += bf2f(e2[6]) + bb.z; av[7] += bf2f(e2[7]) + bb.w;
    }
    va.x += ga.x * av[0]; va.y += ga.y * av[1];
    va.z += ga.z * av[2]; va.w += ga.w * av[3];
    vb.x += gb.x * av[4]; vb.y += gb.y * av[5];
    vb.z += gb.z * av[6]; vb.w += gb.w * av[7];
    float ssq = va.x*va.x + va.y*va.y + va.z*va.z + va.w*va.w
              + vb.x*vb.x + vb.y*vb.y + vb.z*vb.z + vb.w*vb.w;
    if (lane == 0) ssq -= va.x * va.x;   // exclude time component
    float tot = wave_sum(ssq);
    if (lane == 0) va.x = sqrtf(1.f + tot);
    zr[lane * 2] = va; zr[lane * 2 + 1] = vb;
    // layernorm + modulate
    float s = va.x + va.y + va.z + va.w + vb.x + vb.y + vb.z + vb.w;
    float mean = wave_sum(s) * (1.f / DMODEL);
    float d0 = va.x - mean, d1 = va.y - mean, d2 = va.z - mean, d3 = va.w - mean;
    float d4 = vb.x - mean, d5 = vb.y - mean, d6 = vb.z - mean, d7 = vb.w - mean;
    float sq2 = d0*d0 + d1*d1 + d2*d2 + d3*d3 + d4*d4 + d5*d5 + d6*d6 + d7*d7;
    float rstd = rsqrtf(wave_sum(sq2) * (1.f / DMODEL) + 1e-6f);
    const float* ab = adaLN + b * (6 * DMODEL);
    const float4* scp = (const float4*)(ab + sc_off);
    const float4* shp = (const float4*)(ab + sh_off);
    float4 sca = scp[lane * 2], scb = scp[lane * 2 + 1];
    float4 sha = shp[lane * 2], shb = shp[lane * 2 + 1];
    uint4 pk;
    pk.x = (unsigned)f2bf(d0 * rstd * (1.f + sca.x) + sha.x) |
           ((unsigned)f2bf(d1 * rstd * (1.f + sca.y) + sha.y) << 16);
    pk.y = (unsigned)f2bf(d2 * rstd * (1.f + sca.z) + sha.z) |
           ((unsigned)f2bf(d3 * rstd * (1.f + sca.w) + sha.w) << 16);
    pk.z = (unsigned)f2bf(d4 * rstd * (1.f + scb.x) + shb.x) |
           ((unsigned)f2bf(d5 * rstd * (1.f + scb.y) + shb.y) << 16);
    pk.w = (unsigned)f2bf(d6 * rstd * (1.f + scb.z) + shb.z) |
           ((unsigned)f2bf(d7 * rstd * (1.f + scb.w) + shb.w) << 16);
    ((uint4*)(out + (size_t)row * DMODEL))[lane] = pk;
}

__global__ __launch_bounds__(256) void resid_final_kernel(const float* __restrict__ z,
                                                          const ushort_t* __restrict__ add,
                                                          const ushort_t* __restrict__ add2,
                                                          const float* __restrict__ abias,
                                                          const float* __restrict__ adaG, int g_off,
                                                          const float* __restrict__ mask,
                                                          float* __restrict__ out) {
    int lane = threadIdx.x & 63;
    int row = blockIdx.x * 4 + (threadIdx.x >> 6);
    int b = row >> 10;
    const float4* zr = (const float4*)(z + (size_t)row * DMODEL);
    float4 va = zr[lane * 2], vb = zr[lane * 2 + 1];
    uint4 a4 = ((const uint4*)(add + (size_t)row * DMODEL))[lane];
    uint4 a42 = ((const uint4*)(add2 + (size_t)row * DMODEL))[lane];
    const float4* gp = (const float4*)(adaG + b * (6 * DMODEL) + g_off);
    float4 ga = gp[lane * 2], gb = gp[lane * 2 + 1];
    const ushort_t* e = (const ushort_t*)&a4;
    const ushort_t* e2 = (const ushort_t*)&a42;
    float4 ba = ((const float4*)abias)[lane * 2];
    float4 bb = ((const float4*)abias)[lane * 2 + 1];
    va.x += ga.x * (bf2f(e[0]) + bf2f(e2[0]) + ba.x);
    va.y += ga.y * (bf2f(e[1]) + bf2f(e2[1]) + ba.y);
    va.z += ga.z * (bf2f(e[2]) + bf2f(e2[2]) + ba.z);
    va.w += ga.w * (bf2f(e[3]) + bf2f(e2[3]) + ba.w);
    vb.x += gb.x * (bf2f(e[4]) + bf2f(e2[4]) + bb.x);
    vb.y += gb.y * (bf2f(e[5]) + bf2f(e2[5]) + bb.y);
    vb.z += gb.z * (bf2f(e[6]) + bf2f(e2[6]) + bb.z);
    vb.w += gb.w * (bf2f(e[7]) + bf2f(e2[7]) + bb.w);
    float ssq = va.x*va.x + va.y*va.y + va.z*va.z + va.w*va.w
              + vb.x*vb.x + vb.y*vb.y + vb.z*vb.z + vb.w*vb.w;
    if (lane == 0) ssq -= va.x * va.x;
    float tot = wave_sum(ssq);
    if (lane == 0) va.x = sqrtf(1.f + tot);
    float m = mask[row];
    if (m == 0.f) {
        va.x = va.y = va.z = va.w = 0.f;
        vb.x = vb.y = vb.z = vb.w = 0.f;
    }
    float4* orow = (float4*)(out + (size_t)row * DMODEL);
    orow[lane * 2] = va; orow[lane * 2 + 1] = vb;
}

// ---------------- MFMA flash attention (R13-proven: 8 waves, QBLK=128, no-max exp2) ----------------
__global__ __launch_bounds__(512) void flash_attn_mfma(const ushort_t* __restrict__ qkv,
                                                       const float* __restrict__ mask,
                                                       ushort_t* __restrict__ ctx) {
    __shared__ ushort_t Kls[64 * 64];
    __shared__ ushort_t Vt[64 * 64];
    __shared__ ushort_t Pls[8][16 * 64];
    __shared__ float Mall[NTOK];   // whole mask row for this batch (4KB)

    const int tid = threadIdx.x;
    const int lane = tid & 63, w = tid >> 6;
    const int c = lane & 15, g = lane >> 4;
    const int bh = blockIdx.x;
    const int q0 = blockIdx.y * 128;
    const int b = bh >> 3, h = bh & 7;

    const ushort_t* qptr = qkv + (size_t)(b * NTOK + q0 + w * 16 + c) * QKVSTR + h * HDIM + g * 8;
    bf16x8 aq0 = *(const bf16x8*)(qptr);
    bf16x8 aq1 = *(const bf16x8*)(qptr + 32);

    const float mq = mask[b * NTOK + q0 + w * 16 + c];

    #pragma unroll
    for (int i = 0; i < 2; i++) Mall[tid + i * 512] = mask[b * NTOK + tid + i * 512];

    f32x4 o[4];
    #pragma unroll
    for (int j = 0; j < 4; j++) { f32x4 zz = {0.f,0.f,0.f,0.f}; o[j] = zz; }
    float l_run = 0.f;

    const int srow = lane >> 3, qp = lane & 7, ql = qp ^ srow;
    const int kp = tid & 31, dg = tid >> 5;

    char* Pw = (char*)&Pls[w][0];
    const int cswz = (c & 7) << 4;

    for (int kt = 0; kt < NTOK / 64; kt++) {
        const int k0 = kt * 64;
        __syncthreads();
        {
            int row = w * 8 + srow;
            const ushort_t* src = qkv + (size_t)(b * NTOK + k0 + row) * QKVSTR + 512 + h * HDIM + ql * 8;
            __builtin_amdgcn_global_load_lds((const __attribute__((address_space(1))) void*)src,
                                             (__attribute__((address_space(3))) void*)(Kls + w * 512),
                                             16, 0, 0);
        }
        {
            const ushort_t* v0 = qkv + (size_t)(b * NTOK + k0 + 2 * kp) * QKVSTR + 1024 + h * HDIM + dg * 4;
            uint2 r0 = *(const uint2*)v0;
            uint2 r1 = *(const uint2*)(v0 + QKVSTR);
            const ushort_t* e0 = (const ushort_t*)&r0;
            const ushort_t* e1 = (const ushort_t*)&r1;
            unsigned* VtU = (unsigned*)Vt;
            #pragma unroll
            for (int i = 0; i < 4; i++) {
                int d = dg * 4 + i;
                unsigned pk = (unsigned)e0[i] | ((unsigned)e1[i] << 16);
                VtU[d * 32 + (((kp >> 2) ^ (d & 7)) << 2) + (kp & 3)] = pk;
            }
        }
        __syncthreads();

        f32x4 s[4];
        #pragma unroll
        for (int j = 0; j < 4; j++) { f32x4 zz = {0.f,0.f,0.f,0.f}; s[j] = zz; }
        __builtin_amdgcn_s_setprio(1);
        #pragma unroll
        for (int j = 0; j < 4; j++) {
            int row = j * 16 + c;
            bf16x8 ak0 = *(const bf16x8*)(Kls + row * 64 + ((g ^ (row & 7)) << 3));
            bf16x8 ak1 = *(const bf16x8*)(Kls + row * 64 + (((4 + g) ^ (row & 7)) << 3));
            s[j] = __builtin_amdgcn_mfma_f32_16x16x32_bf16(ak0, aq0, s[j], 0, 0, 0);
            s[j] = __builtin_amdgcn_mfma_f32_16x16x32_bf16(ak1, aq1, s[j], 0, 0, 0);
        }
        __builtin_amdgcn_s_setprio(0);

        #pragma unroll
        for (int j = 0; j < 4; j++) {
            float4 mk4 = *(const float4*)&Mall[k0 + j * 16 + 4 * g];
            const float* mkp = (const float*)&mk4;
            float p[4];
            #pragma unroll
            for (int r = 0; r < 4; r++) {
                float mm = mq * mkp[r];
                float sv = s[j][r] + (mm == 0.f ? -14427.0f : mm * LOG2E);
                p[r] = exp2f(sv);
                l_run += p[r];
            }
            uint2 pk2;
            pk2.x = (unsigned)f2bf(p[0]) | ((unsigned)f2bf(p[1]) << 16);
            pk2.y = (unsigned)f2bf(p[2]) | ((unsigned)f2bf(p[3]) << 16);
            *(uint2*)(Pw + c * 128 + ((j * 32 + g * 8) ^ cswz)) = pk2;
        }

        __builtin_amdgcn_s_setprio(1);
        #pragma unroll
        for (int kk = 0; kk < 2; kk++) {
            bf16x8 pa = *(const bf16x8*)(Pw + c * 128 + ((kk * 64 + g * 16) ^ cswz));
            #pragma unroll
            for (int j = 0; j < 4; j++) {
                int vr = j * 16 + c;
                bf16x8 bv = *(const bf16x8*)(Vt + vr * 64 + (((kk * 4 + g) ^ (vr & 7)) << 3));
                o[j] = __builtin_amdgcn_mfma_f32_16x16x32_bf16(pa, bv, o[j], 0, 0, 0);
            }
        }
        __builtin_amdgcn_s_setprio(0);
    }

    l_run += __shfl_xor(l_run, 16);
    l_run += __shfl_xor(l_run, 32);

    float invr[4];
    #pragma unroll
    for (int r = 0; r < 4; r++) invr[r] = 1.f / __shfl(l_run, (g << 4) + 4 * g + r);
    #pragma unroll
    for (int r = 0; r < 4; r++) {
        size_t row = (size_t)(b * NTOK + q0 + w * 16 + 4 * g + r) * DMODEL + h * HDIM;
        #pragma unroll
        for (int j = 0; j < 4; j++)
            ctx[row + j * 16 + c] = f2bf(o[j][r] * invr[r]);
    }
}

// ---------------- launch ----------------

extern "C" void kernel_launch(void* const* d_in, const int* in_sizes, int n_in,
                              void* d_out, int out_size, void* d_ws, size_t ws_size,
                              hipStream_t stream) {
    const float* t    = (const float*)d_in[0];
    const float* x    = (const float*)d_in[1];
    const float* mask = (const float*)d_in[2];
    const float* pe   = (const float*)d_in[3];
    const float* tw1  = (const float*)d_in[4];
    const float* tb1  = (const float*)d_in[5];
    const float* tw2  = (const float*)d_in[6];
    const float* tb2  = (const float*)d_in[7];
    const float* Wq   = (const float*)d_in[8];
    const float* bq   = (const float*)d_in[9];
    const float* Wk   = (const float*)d_in[10];
    const float* bk   = (const float*)d_in[11];
    const float* Wv   = (const float*)d_in[12];
    const float* bv   = (const float*)d_in[13];
    const float* W1   = (const float*)d_in[14];
    const float* b1   = (const float*)d_in[15];
    const float* W2   = (const float*)d_in[16];
    const float* b2   = (const float*)d_in[17];
    const float* Wada = (const float*)d_in[18];
    const float* bada = (const float*)d_in[19];
    float* out = (float*)d_out;

    const bool hoist = ws_size >= 113129472ull;
    const int WL = hoist ? NLAYER : 1;

    float* z      = (float*)d_ws;
    ushort_t* cxb = (ushort_t*)(z + (size_t)ROWS * DMODEL);       // partial0 / ctx (8.4MB)
    ushort_t* cxb2 = cxb + (size_t)ROWS * DMODEL;                 // partial1 (8.4MB)
    ushort_t* qkv = cxb2 + (size_t)ROWS * DMODEL;
    ushort_t* mid = qkv;
    ushort_t* hb  = qkv + (size_t)ROWS * 2048;
    ushort_t* wqkv_t = hb + (size_t)ROWS * DMODEL;
    ushort_t* w1_t   = wqkv_t + (size_t)WL * QKVSTR * 512;
    ushort_t* w2_t   = w1_t + (size_t)WL * 2048 * 512;
    float* bqkv  = (float*)(w2_t + (size_t)WL * 512 * 2048);
    float* fzero = bqkv + NLAYER * QKVSTR;
    float* temb  = fzero + 512;
    float* cmid  = temb + BATCH * 256;
    float* scs   = cmid + BATCH * DMODEL;
    float* part  = scs + BATCH * DMODEL;
    float* ada_all = part + 4 * 8 * (NLAYER * 3072);

    init_z_kernel<<<ROWS * DMODEL / 4 / 256, 256, 0, stream>>>(x, pe, z);
    temb_kernel<<<BATCH, 128, 0, stream>>>(t, temb);
    pack_bias<<<(NLAYER * QKVSTR + 255) / 256, 256, 0, stream>>>(bq, bk, bv, bqkv);
    zero512<<<2, 256, 0, stream>>>(fzero);

    skinny_part<<<dim3(2, 2, 1), 256, 0, stream>>>(temb, tw1, part, 256, 512, 512);
    skinny_reduce<1><<<16, 256, 0, stream>>>(part, tb1, cmid, 2, 512, 512);
    skinny_part<<<dim3(2, 4, 1), 256, 0, stream>>>(cmid, tw2, part, 512, 512, 512);
    skinny_reduce<1><<<16, 256, 0, stream>>>(part, tb2, scs, 4, 512, 512);
    skinny_part<<<dim3(12, 4, NLAYER), 256, 0, stream>>>(scs, Wada, part, 512, 3072, NLAYER * 3072);
    skinny_reduce<0><<<(8 * NLAYER * 3072 + 255) / 256, 256, 0, stream>>>(
        part, bada, ada_all, 4, 3072, NLAYER * 3072);

    if (hoist) {
        transp_all<<<dim3(2816, 1, NLAYER), 256, 0, stream>>>(Wq, Wk, Wv, W1, W2,
                                                              wqkv_t, w1_t, w2_t);
    }

    dim3 gqkv(ROWS / 128, QKVSTR / 128);
    dim3 gmlp1(ROWS / 128, 2048 / 128);
    dim3 gmlp2(ROWS / 128, DMODEL / 128, 2);   // split-K=2
    dim3 ga(BATCH * NHEAD, NTOK / 128);

    ln_mod_kernel<<<ROWS / 4, 256, 0, stream>>>(z, ada_all, hb, 0, 512);

    for (int i = 0; i < NLAYER; i++) {
        const float* ada = ada_all + (size_t)i * 8 * 3072;

        const ushort_t* wq_i = hoist ? wqkv_t + (size_t)i * QKVSTR * 512 : wqkv_t;
        const ushort_t* w1_i = hoist ? w1_t + (size_t)i * 2048 * 512 : w1_t;
        const ushort_t* w2_i = hoist ? w2_t + (size_t)i * 512 * 2048 : w2_t;

        if (!hoist) {
            transp_all<<<dim3(2816, 1, 1), 256, 0, stream>>>(Wq + (size_t)i * 512 * 512,
                                                             Wk + (size_t)i * 512 * 512,
                                                             Wv + (size_t)i * 512 * 512,
                                                             W1 + (size_t)i * 512 * 2048,
                                                             W2 + (size_t)i * 2048 * 512,
                                                             wqkv_t, w1_t, w2_t);
        }

        mfma_gemm<0, 1, 1, 0><<<gqkv, 256, 0, stream>>>(hb, wq_i, bqkv + i * QKVSTR, qkv,
                                                        ROWS, QKVSTR, DMODEL);

        flash_attn_mfma<<<ga, 512, 0, stream>>>(qkv, mask, cxb);

        resid_ln_kernel<0><<<ROWS / 4, 256, 0, stream>>>(z, cxb, nullptr, nullptr,
                                                         ada, 2 * DMODEL,
                                                         ada, 3 * DMODEL, 4 * DMODEL, hb);

        mfma_gemm<1, 1, 0, 0><<<gmlp1, 256, 0, stream>>>(hb, w1_i, b1 + (size_t)i * 4 * DMODEL, mid,
                                                         ROWS, 4 * DMODEL, DMODEL);
        mfma_gemm<0, 1, 0, 1><<<gmlp2, 256, 0, stream>>>(mid, w2_i, fzero, cxb,
                                                         ROWS, DMODEL, 4 * DMODEL);

        if (i < NLAYER - 1) {
            const float* adan = ada_all + (size_t)(i + 1) * 8 * 3072;
            resid_ln_kernel<1><<<ROWS / 4, 256, 0, stream>>>(z, cxb, cxb2, b2 + (size_t)i * DMODEL,
                                                             ada, 5 * DMODEL,
                                                             adan, 0, 512, hb);
        } else {
            resid_final_kernel<<<ROWS / 4, 256, 0, stream>>>(z, cxb, cxb2, b2 + (size_t)i * DMODEL,
                                                             ada, 5 * DMODEL, mask, out);
        }
    }
}

// Round 18
// 891.950 us; speedup vs baseline: 1.0483x; 1.0232x over previous
//
#include <hip/hip_runtime.h>
#include <hip/hip_bf16.h>
#include <math.h>

#define NTOK 1024
#define DMODEL 512
#define NHEAD 8
#define HDIM 64
#define BATCH 8
#define NLAYER 6
#define ROWS (BATCH*NTOK)   // 8192
#define QKVSTR 1536
#define LOG2E 1.44269504f

typedef __attribute__((ext_vector_type(8))) short bf16x8;
typedef __attribute__((ext_vector_type(4))) float f32x4;
typedef unsigned short ushort_t;

// ---------------- device helpers ----------------

__device__ __forceinline__ float silu_f(float x) { return x / (1.f + expf(-x)); }

__device__ __forceinline__ float gelu_tanh_f(float x) {
    float x3 = x * x * x;
    float y2 = 1.5957691216057308f * (x + 0.044715f * x3);
    float e = __builtin_amdgcn_exp2f(-y2 * LOG2E);
    return x / (1.f + e);
}

__device__ __forceinline__ unsigned short f2bf(float x) {
    __hip_bfloat16 b = __float2bfloat16(x);
    return *reinterpret_cast<unsigned short*>(&b);
}

__device__ __forceinline__ float bf2f(unsigned short u) {
    union { float f; unsigned v; } c;
    c.v = (unsigned)u << 16;
    return c.f;
}

__device__ __forceinline__ float wave_sum(float v) {
    #pragma unroll
    for (int o = 1; o < 64; o <<= 1) v += __shfl_xor(v, o);
    return v;
}

// ---------------- small kernels ----------------

__global__ __launch_bounds__(256) void init_z_kernel(const float* __restrict__ x,
                                                     const float* __restrict__ pe,
                                                     float* __restrict__ z) {
    int i = blockIdx.x * 256 + threadIdx.x;
    const int C4 = DMODEL / 4;
    int row = i / C4;
    int col4 = i - row * C4;
    int n = row & (NTOK - 1);
    float4 xv = ((const float4*)x)[i];
    float4 pv = ((const float4*)pe)[n * C4 + col4];
    float4 o;
    o.x = 2.f * xv.x + pv.x;
    o.y = 2.f * xv.y + pv.y;
    o.z = 2.f * xv.z + pv.z;
    o.w = 2.f * xv.w + pv.w;
    ((float4*)z)[i] = o;
}

__global__ void temb_kernel(const float* __restrict__ t, float* __restrict__ temb) {
    int b = blockIdx.x;
    int j = threadIdx.x;   // 128
    float f = expf(-9.210340371976184f * (float)j / 128.f);
    float a = t[b] * f;
    temb[b * 256 + j] = cosf(a);
    temb[b * 256 + 128 + j] = sinf(a);
}

// ---------------- skinny (M=8) k-split GEMM ----------------
__global__ __launch_bounds__(256) void skinny_part(const float* __restrict__ A,
                                                   const float* __restrict__ W,
                                                   float* __restrict__ part,
                                                   int K, int N, int NL) {
    __shared__ float Als[8][128];
    const int l = blockIdx.z;
    const int n = blockIdx.x * 256 + threadIdx.x;
    const int kc = blockIdx.y;
    const int kbase = kc * 128;
    for (int i = threadIdx.x; i < 8 * 128; i += 256) {
        int b = i >> 7, k = i & 127;
        Als[b][k] = A[b * K + kbase + k];
    }
    __syncthreads();
    float acc[8] = {};
    const float* wp = W + (size_t)l * K * N + (size_t)kbase * N + n;
    for (int k = 0; k < 128; k += 4) {
        float w0 = wp[0];
        float w1 = wp[N];
        float w2 = wp[2 * N];
        float w3 = wp[3 * N];
        wp += 4 * (size_t)N;
        #pragma unroll
        for (int b = 0; b < 8; b++)
            acc[b] += Als[b][k] * w0 + Als[b][k + 1] * w1 + Als[b][k + 2] * w2 + Als[b][k + 3] * w3;
    }
    #pragma unroll
    for (int b = 0; b < 8; b++)
        part[((size_t)kc * 8 + b) * NL + (size_t)l * N + n] = acc[b];
}

template<int ACT>
__global__ __launch_bounds__(256) void skinny_reduce(const float* __restrict__ part,
                                                     const float* __restrict__ bias,
                                                     float* __restrict__ out,
                                                     int KC, int N, int NL) {
    int i = blockIdx.x * 256 + threadIdx.x;
    if (i >= 8 * NL) return;
    int b = i / NL, n = i - b * NL;
    float s = bias[n];
    for (int kc = 0; kc < KC; kc++) s += part[((size_t)kc * 8 + b) * NL + n];
    if (ACT == 1) s = silu_f(s);
    int l = n / N, nl = n - l * N;
    out[((size_t)l * 8 + b) * N + nl] = s;
}

// ---------------- weight prep: 5 transposes per layer; blockIdx.z = layer ----------------
__global__ __launch_bounds__(256) void transp_all(const float* __restrict__ Wq,
                                                  const float* __restrict__ Wk,
                                                  const float* __restrict__ Wv,
                                                  const float* __restrict__ W1,
                                                  const float* __restrict__ W2,
                                                  ushort_t* __restrict__ wqkv_t,
                                                  ushort_t* __restrict__ w1_t,
                                                  ushort_t* __restrict__ w2_t) {
    __shared__ float tile[32][33];
    const int L = blockIdx.z;
    Wq += (size_t)L * 512 * 512;
    Wk += (size_t)L * 512 * 512;
    Wv += (size_t)L * 512 * 512;
    W1 += (size_t)L * 512 * 2048;
    W2 += (size_t)L * 2048 * 512;
    wqkv_t += (size_t)L * QKVSTR * 512;
    w1_t += (size_t)L * 2048 * 512;
    w2_t += (size_t)L * 512 * 2048;
    int blk = blockIdx.x;
    const float* src; ushort_t* dst; int K, N, k0, n0;
    if (blk < 768) {
        int zz = blk >> 8, rem = blk & 255;
        k0 = (rem >> 4) * 32; n0 = (rem & 15) * 32;
        src = zz == 0 ? Wq : (zz == 1 ? Wk : Wv);
        dst = wqkv_t + zz * 512 * 512;
        K = 512; N = 512;
    } else if (blk < 1792) {
        int rem = blk - 768;
        n0 = (rem & 63) * 32; k0 = (rem >> 6) * 32;
        src = W1; dst = w1_t; K = 512; N = 2048;
    } else {
        int rem = blk - 1792;
        n0 = (rem & 15) * 32; k0 = (rem >> 4) * 32;
        src = W2; dst = w2_t; K = 2048; N = 512;
    }
    int c = threadIdx.x & 31, r8 = threadIdx.x >> 5;
    #pragma unroll
    for (int i = 0; i < 4; i++) {
        int r = r8 + i * 8;
        tile[r][c] = src[(size_t)(k0 + r) * N + n0 + c];
    }
    __syncthreads();
    #pragma unroll
    for (int i = 0; i < 4; i++) {
        int rr = r8 + i * 8;
        dst[(size_t)(n0 + rr) * K + k0 + c] = f2bf(tile[c][rr]);
    }
}

__global__ void pack_bias(const float* __restrict__ bq, const float* __restrict__ bk,
                          const float* __restrict__ bv, float* __restrict__ bqkv) {
    int idx = blockIdx.x * 256 + threadIdx.x;
    if (idx >= NLAYER * QKVSTR) return;
    int l = idx / QKVSTR, n = idx - l * QKVSTR;
    float v = (n < 512) ? bq[l * 512 + n] : (n < 1024) ? bk[l * 512 + n - 512] : bv[l * 512 + n - 1024];
    bqkv[idx] = v;
}

// ---------------- bf16 MFMA GEMM (2-phase dbuf + LDS-coalesced epilogue) ----------------
// SPLITK: blockIdx.z selects K-half; partial written to Cout + z*M*N (bf16 only)
// NOBIAS: skip bias load entirely (bias folded downstream)
template<int ACT, int OUTBF, int QPRESCALE, int SPLITK, int NOBIAS>
__global__ __launch_bounds__(256) void mfma_gemm(const ushort_t* __restrict__ A,
                                                 const ushort_t* __restrict__ Bt,
                                                 const float* __restrict__ bias,
                                                 void* __restrict__ Cout,
                                                 int M, int N, int K) {
    __shared__ ushort_t smem[4 * 128 * 64];   // 64KB: A0|A1|B0|B1; epilogue reuses as C[128][136]
    const int tid = threadIdx.x;
    const int lane = tid & 63, wv = tid >> 6;
    const int wm = (wv >> 1) * 64, wn = (wv & 1) * 64;
    const int lrow = lane & 15, lk = lane >> 4;
    const int m0 = blockIdx.x * 128, n0 = blockIdx.y * 128;
    const int srow = lane >> 3;
    const int qp = lane & 7;
    const int ql = qp ^ srow;

    int Keff = K;
    if (SPLITK) {
        Keff = K >> 1;
        const size_t koff = (size_t)blockIdx.z * Keff;
        A += koff;
        Bt += koff;
        Cout = (void*)((ushort_t*)Cout + (size_t)blockIdx.z * M * N);
    }

    f32x4 acc[4][4];
    #pragma unroll
    for (int i = 0; i < 4; i++)
        #pragma unroll
        for (int j = 0; j < 4; j++) {
            f32x4 zz = {0.f, 0.f, 0.f, 0.f};
            acc[i][j] = zz;
        }

    const int nK = Keff >> 6;

    auto STAGE = [&](int p, int ks) {
        const int k0 = ks << 6;
        ushort_t* Ad = smem + p * 8192;
        ushort_t* Bd = smem + 16384 + p * 8192;
        #pragma unroll
        for (int it = 0; it < 4; it++) {
            int chunk = wv * 4 + it;
            int row = chunk * 8 + srow;
            const ushort_t* srcA = A + (size_t)(m0 + row) * K + k0 + ql * 8;
            const ushort_t* srcB = Bt + (size_t)(n0 + row) * K + k0 + ql * 8;
            __builtin_amdgcn_global_load_lds((const __attribute__((address_space(1))) void*)srcA,
                                             (__attribute__((address_space(3))) void*)(Ad + chunk * 512),
                                             16, 0, 0);
            __builtin_amdgcn_global_load_lds((const __attribute__((address_space(1))) void*)srcB,
                                             (__attribute__((address_space(3))) void*)(Bd + chunk * 512),
                                             16, 0, 0);
        }
    };

    STAGE(0, 0);
    int cur = 0;
    for (int ks = 0; ks < nK; ks++) {
        if (ks + 1 < nK) {
            STAGE(cur ^ 1, ks + 1);
            asm volatile("s_waitcnt vmcnt(8)" ::: "memory");
        } else {
            asm volatile("s_waitcnt vmcnt(0)" ::: "memory");
        }
        __builtin_amdgcn_s_barrier();
        asm volatile("" ::: "memory");

        const ushort_t* Ab = smem + cur * 8192;
        const ushort_t* Bb = smem + 16384 + cur * 8192;
        #pragma unroll
        for (int kk = 0; kk < 2; kk++) {
            bf16x8 af[4], bfr[4];
            #pragma unroll
            for (int f = 0; f < 4; f++) {
                int ar = wm + f * 16 + lrow;
                af[f] = *(const bf16x8*)(Ab + ar * 64 + (((kk * 4 + lk) ^ (ar & 7)) << 3));
                int br = wn + f * 16 + lrow;
                bfr[f] = *(const bf16x8*)(Bb + br * 64 + (((kk * 4 + lk) ^ (br & 7)) << 3));
            }
            #pragma unroll
            for (int i = 0; i < 4; i++)
                #pragma unroll
                for (int j = 0; j < 4; j++)
                    acc[i][j] = __builtin_amdgcn_mfma_f32_16x16x32_bf16(af[i], bfr[j], acc[i][j], 0, 0, 0);
        }
        asm volatile("" ::: "memory");
        __builtin_amdgcn_s_barrier();
        cur ^= 1;
    }

    if (OUTBF) {
        __syncthreads();   // drain LDS reads before overwriting smem with C
        #pragma unroll
        for (int j = 0; j < 4; j++) {
            int coll = wn + j * 16 + lrow;
            float bcol = NOBIAS ? 0.f : bias[n0 + coll];
            #pragma unroll
            for (int i = 0; i < 4; i++) {
                #pragma unroll
                for (int r = 0; r < 4; r++) {
                    int rowl = wm + i * 16 + lk * 4 + r;
                    float v = acc[i][j][r] + bcol;
                    if (ACT == 1) v = gelu_tanh_f(v);
                    if (QPRESCALE && (n0 + coll) < 512) v *= 0.125f * LOG2E;
                    smem[rowl * 136 + coll] = f2bf(v);
                }
            }
        }
        __syncthreads();
        ushort_t* Co = (ushort_t*)Cout;
        #pragma unroll
        for (int pass = 0; pass < 8; pass++) {
            int rowl = pass * 16 + (tid >> 4);
            int cseg = (tid & 15) * 8;
            uint4 vv = *(const uint4*)(smem + rowl * 136 + cseg);
            *(uint4*)(Co + (size_t)(m0 + rowl) * N + n0 + cseg) = vv;
        }
    } else {
        #pragma unroll
        for (int j = 0; j < 4; j++) {
            int col = n0 + wn + j * 16 + lrow;
            float bcol = NOBIAS ? 0.f : bias[col];
            #pragma unroll
            for (int i = 0; i < 4; i++)
                #pragma unroll
                for (int r = 0; r < 4; r++) {
                    int row = m0 + wm + i * 16 + lk * 4 + r;
                    float v = acc[i][j][r] + bcol;
                    if (ACT == 1) v = gelu_tanh_f(v);
                    ((float*)Cout)[(size_t)row * N + col] = v;
                }
        }
    }
}

// ---------------- fused elementwise (wave-per-row, barrier-free) ----------------

__global__ __launch_bounds__(256) void ln_mod_kernel(const float* __restrict__ z,
                                                     const float* __restrict__ ada,
                                                     ushort_t* __restrict__ out,
                                                     int sh_off, int sc_off) {
    int lane = threadIdx.x & 63;
    int row = blockIdx.x * 4 + (threadIdx.x >> 6);
    int b = row >> 10;
    const float4* zr = (const float4*)(z + (size_t)row * DMODEL);
    float4 va = zr[lane * 2], vb = zr[lane * 2 + 1];
    float s = va.x + va.y + va.z + va.w + vb.x + vb.y + vb.z + vb.w;
    float mean = wave_sum(s) * (1.f / DMODEL);
    float d0 = va.x - mean, d1 = va.y - mean, d2 = va.z - mean, d3 = va.w - mean;
    float d4 = vb.x - mean, d5 = vb.y - mean, d6 = vb.z - mean, d7 = vb.w - mean;
    float ssq = d0*d0 + d1*d1 + d2*d2 + d3*d3 + d4*d4 + d5*d5 + d6*d6 + d7*d7;
    float rstd = rsqrtf(wave_sum(ssq) * (1.f / DMODEL) + 1e-6f);
    const float* ab = ada + b * (6 * DMODEL);
    const float4* scp = (const float4*)(ab + sc_off);
    const float4* shp = (const float4*)(ab + sh_off);
    float4 sca = scp[lane * 2], scb = scp[lane * 2 + 1];
    float4 sha = shp[lane * 2], shb = shp[lane * 2 + 1];
    uint4 pk;
    pk.x = (unsigned)f2bf(d0 * rstd * (1.f + sca.x) + sha.x) |
           ((unsigned)f2bf(d1 * rstd * (1.f + sca.y) + sha.y) << 16);
    pk.y = (unsigned)f2bf(d2 * rstd * (1.f + sca.z) + sha.z) |
           ((unsigned)f2bf(d3 * rstd * (1.f + sca.w) + sha.w) << 16);
    pk.z = (unsigned)f2bf(d4 * rstd * (1.f + scb.x) + shb.x) |
           ((unsigned)f2bf(d5 * rstd * (1.f + scb.y) + shb.y) << 16);
    pk.w = (unsigned)f2bf(d6 * rstd * (1.f + scb.z) + shb.z) |
           ((unsigned)f2bf(d7 * rstd * (1.f + scb.w) + shb.w) << 16);
    ((uint4*)(out + (size_t)row * DMODEL))[lane] = pk;
}

// TWO=1: add = partial0, add2 = partial1, abias added inside g*(...)
template<int TWO>
__global__ __launch_bounds__(256) void resid_ln_kernel(float* __restrict__ z,
                                                       const ushort_t* __restrict__ add,
                                                       const ushort_t* __restrict__ add2,
                                                       const float* __restrict__ abias,
                                                       const float* __restrict__ adaG, int g_off,
                                                       const float* __restrict__ adaLN, int sh_off, int sc_off,
                                                       ushort_t* __restrict__ out) {
    int lane = threadIdx.x & 63;
    int row = blockIdx.x * 4 + (threadIdx.x >> 6);
    int b = row >> 10;
    float4* zr = (float4*)(z + (size_t)row * DMODEL);
    float4 va = zr[lane * 2], vb = zr[lane * 2 + 1];
    uint4 a4 = ((const uint4*)(add + (size_t)row * DMODEL))[lane];
    const float4* gp = (const float4*)(adaG + b * (6 * DMODEL) + g_off);
    float4 ga = gp[lane * 2], gb = gp[lane * 2 + 1];
    const ushort_t* e = (const ushort_t*)&a4;
    float av[8];
    #pragma unroll
    for (int i = 0; i < 8; i++) av[i] = bf2f(e[i]);
    if (TWO) {
        uint4 a42 = ((const uint4*)(add2 + (size_t)row * DMODEL))[lane];
        const ushort_t* e2 = (const ushort_t*)&a42;
        float4 ba = ((const float4*)abias)[lane * 2];
        float4 bb = ((const float4*)abias)[lane * 2 + 1];
        av[0] += bf2f(e2[0]) + ba.x; av[1] += bf2f(e2[1]) + ba.y;
        av[2] += bf2f(e2[2]) + ba.z; av[3] += bf2f(e2[3]) + ba.w;
        av[4] += bf2f(e2[4]) + bb.x; av[5] += bf2f(e2[5]) + bb.y;
        av[6] += bf2f(e2[6]) + bb.z; av[7] += bf2f(e2[7]) + bb.w;
    }
    va.x += ga.x * av[0]; va.y += ga.y * av[1];
    va.z += ga.z * av[2]; va.w += ga.w * av[3];
    vb.x += gb.x * av[4]; vb.y += gb.y * av[5];
    vb.z += gb.z * av[6]; vb.w += gb.w * av[7];
    float ssq = va.x*va.x + va.y*va.y + va.z*va.z + va.w*va.w
              + vb.x*vb.x + vb.y*vb.y + vb.z*vb.z + vb.w*vb.w;
    if (lane == 0) ssq -= va.x * va.x;   // exclude time component
    float tot = wave_sum(ssq);
    if (lane == 0) va.x = sqrtf(1.f + tot);
    zr[lane * 2] = va; zr[lane * 2 + 1] = vb;
    // layernorm + modulate
    float s = va.x + va.y + va.z + va.w + vb.x + vb.y + vb.z + vb.w;
    float mean = wave_sum(s) * (1.f / DMODEL);
    float d0 = va.x - mean, d1 = va.y - mean, d2 = va.z - mean, d3 = va.w - mean;
    float d4 = vb.x - mean, d5 = vb.y - mean, d6 = vb.z - mean, d7 = vb.w - mean;
    float sq2 = d0*d0 + d1*d1 + d2*d2 + d3*d3 + d4*d4 + d5*d5 + d6*d6 + d7*d7;
    float rstd = rsqrtf(wave_sum(sq2) * (1.f / DMODEL) + 1e-6f);
    const float* ab = adaLN + b * (6 * DMODEL);
    const float4* scp = (const float4*)(ab + sc_off);
    const float4* shp = (const float4*)(ab + sh_off);
    float4 sca = scp[lane * 2], scb = scp[lane * 2 + 1];
    float4 sha = shp[lane * 2], shb = shp[lane * 2 + 1];
    uint4 pk;
    pk.x = (unsigned)f2bf(d0 * rstd * (1.f + sca.x) + sha.x) |
           ((unsigned)f2bf(d1 * rstd * (1.f + sca.y) + sha.y) << 16);
    pk.y = (unsigned)f2bf(d2 * rstd * (1.f + sca.z) + sha.z) |
           ((unsigned)f2bf(d3 * rstd * (1.f + sca.w) + sha.w) << 16);
    pk.z = (unsigned)f2bf(d4 * rstd * (1.f + scb.x) + shb.x) |
           ((unsigned)f2bf(d5 * rstd * (1.f + scb.y) + shb.y) << 16);
    pk.w = (unsigned)f2bf(d6 * rstd * (1.f + scb.z) + shb.z) |
           ((unsigned)f2bf(d7 * rstd * (1.f + scb.w) + shb.w) << 16);
    ((uint4*)(out + (size_t)row * DMODEL))[lane] = pk;
}

__global__ __launch_bounds__(256) void resid_final_kernel(const float* __restrict__ z,
                                                          const ushort_t* __restrict__ add,
                                                          const ushort_t* __restrict__ add2,
                                                          const float* __restrict__ abias,
                                                          const float* __restrict__ adaG, int g_off,
                                                          const float* __restrict__ mask,
                                                          float* __restrict__ out) {
    int lane = threadIdx.x & 63;
    int row = blockIdx.x * 4 + (threadIdx.x >> 6);
    int b = row >> 10;
    const float4* zr = (const float4*)(z + (size_t)row * DMODEL);
    float4 va = zr[lane * 2], vb = zr[lane * 2 + 1];
    uint4 a4 = ((const uint4*)(add + (size_t)row * DMODEL))[lane];
    uint4 a42 = ((const uint4*)(add2 + (size_t)row * DMODEL))[lane];
    const float4* gp = (const float4*)(adaG + b * (6 * DMODEL) + g_off);
    float4 ga = gp[lane * 2], gb = gp[lane * 2 + 1];
    const ushort_t* e = (const ushort_t*)&a4;
    const ushort_t* e2 = (const ushort_t*)&a42;
    float4 ba = ((const float4*)abias)[lane * 2];
    float4 bb = ((const float4*)abias)[lane * 2 + 1];
    va.x += ga.x * (bf2f(e[0]) + bf2f(e2[0]) + ba.x);
    va.y += ga.y * (bf2f(e[1]) + bf2f(e2[1]) + ba.y);
    va.z += ga.z * (bf2f(e[2]) + bf2f(e2[2]) + ba.z);
    va.w += ga.w * (bf2f(e[3]) + bf2f(e2[3]) + ba.w);
    vb.x += gb.x * (bf2f(e[4]) + bf2f(e2[4]) + bb.x);
    vb.y += gb.y * (bf2f(e[5]) + bf2f(e2[5]) + bb.y);
    vb.z += gb.z * (bf2f(e[6]) + bf2f(e2[6]) + bb.z);
    vb.w += gb.w * (bf2f(e[7]) + bf2f(e2[7]) + bb.w);
    float ssq = va.x*va.x + va.y*va.y + va.z*va.z + va.w*va.w
              + vb.x*vb.x + vb.y*vb.y + vb.z*vb.z + vb.w*vb.w;
    if (lane == 0) ssq -= va.x * va.x;
    float tot = wave_sum(ssq);
    if (lane == 0) va.x = sqrtf(1.f + tot);
    float m = mask[row];
    if (m == 0.f) {
        va.x = va.y = va.z = va.w = 0.f;
        vb.x = vb.y = vb.z = vb.w = 0.f;
    }
    float4* orow = (float4*)(out + (size_t)row * DMODEL);
    orow[lane * 2] = va; orow[lane * 2 + 1] = vb;
}

// ---------------- MFMA flash attention (R13-proven structure; Mall pre-scaled by log2e) ----------------
__global__ __launch_bounds__(512) void flash_attn_mfma(const ushort_t* __restrict__ qkv,
                                                       const float* __restrict__ mask,
                                                       ushort_t* __restrict__ ctx) {
    __shared__ ushort_t Kls[64 * 64];
    __shared__ ushort_t Vt[64 * 64];
    __shared__ ushort_t Pls[8][16 * 64];
    __shared__ float Mall[NTOK];   // mask row * LOG2E (4KB)

    const int tid = threadIdx.x;
    const int lane = tid & 63, w = tid >> 6;
    const int c = lane & 15, g = lane >> 4;
    const int bh = blockIdx.x;
    const int q0 = blockIdx.y * 128;
    const int b = bh >> 3, h = bh & 7;

    const ushort_t* qptr = qkv + (size_t)(b * NTOK + q0 + w * 16 + c) * QKVSTR + h * HDIM + g * 8;
    bf16x8 aq0 = *(const bf16x8*)(qptr);
    bf16x8 aq1 = *(const bf16x8*)(qptr + 32);

    const float mq = mask[b * NTOK + q0 + w * 16 + c];

    #pragma unroll
    for (int i = 0; i < 2; i++)
        Mall[tid + i * 512] = mask[b * NTOK + tid + i * 512] * LOG2E;

    f32x4 o[4];
    #pragma unroll
    for (int j = 0; j < 4; j++) { f32x4 zz = {0.f,0.f,0.f,0.f}; o[j] = zz; }
    float l_run = 0.f;

    const int srow = lane >> 3, qp = lane & 7, ql = qp ^ srow;
    const int kp = tid & 31, dg = tid >> 5;

    char* Pw = (char*)&Pls[w][0];
    const int cswz = (c & 7) << 4;

    for (int kt = 0; kt < NTOK / 64; kt++) {
        const int k0 = kt * 64;
        __syncthreads();
        {
            int row = w * 8 + srow;
            const ushort_t* src = qkv + (size_t)(b * NTOK + k0 + row) * QKVSTR + 512 + h * HDIM + ql * 8;
            __builtin_amdgcn_global_load_lds((const __attribute__((address_space(1))) void*)src,
                                             (__attribute__((address_space(3))) void*)(Kls + w * 512),
                                             16, 0, 0);
        }
        {
            const ushort_t* v0 = qkv + (size_t)(b * NTOK + k0 + 2 * kp) * QKVSTR + 1024 + h * HDIM + dg * 4;
            uint2 r0 = *(const uint2*)v0;
            uint2 r1 = *(const uint2*)(v0 + QKVSTR);
            const ushort_t* e0 = (const ushort_t*)&r0;
            const ushort_t* e1 = (const ushort_t*)&r1;
            unsigned* VtU = (unsigned*)Vt;
            #pragma unroll
            for (int i = 0; i < 4; i++) {
                int d = dg * 4 + i;
                unsigned pk = (unsigned)e0[i] | ((unsigned)e1[i] << 16);
                VtU[d * 32 + (((kp >> 2) ^ (d & 7)) << 2) + (kp & 3)] = pk;
            }
        }
        __syncthreads();

        f32x4 s[4];
        #pragma unroll
        for (int j = 0; j < 4; j++) { f32x4 zz = {0.f,0.f,0.f,0.f}; s[j] = zz; }
        __builtin_amdgcn_s_setprio(1);
        #pragma unroll
        for (int j = 0; j < 4; j++) {
            int row = j * 16 + c;
            bf16x8 ak0 = *(const bf16x8*)(Kls + row * 64 + ((g ^ (row & 7)) << 3));
            bf16x8 ak1 = *(const bf16x8*)(Kls + row * 64 + (((4 + g) ^ (row & 7)) << 3));
            s[j] = __builtin_amdgcn_mfma_f32_16x16x32_bf16(ak0, aq0, s[j], 0, 0, 0);
            s[j] = __builtin_amdgcn_mfma_f32_16x16x32_bf16(ak1, aq1, s[j], 0, 0, 0);
        }
        __builtin_amdgcn_s_setprio(0);

        #pragma unroll
        for (int j = 0; j < 4; j++) {
            float4 mk4 = *(const float4*)&Mall[k0 + j * 16 + 4 * g];
            const float* mkp = (const float*)&mk4;
            float p[4];
            #pragma unroll
            for (int r = 0; r < 4; r++) {
                float v = mq * mkp[r];          // = mq*mk*log2e (0 iff masked)
                float sv = s[j][r] + (v == 0.f ? -14427.0f : v);
                p[r] = exp2f(sv);
                l_run += p[r];
            }
            uint2 pk2;
            pk2.x = (unsigned)f2bf(p[0]) | ((unsigned)f2bf(p[1]) << 16);
            pk2.y = (unsigned)f2bf(p[2]) | ((unsigned)f2bf(p[3]) << 16);
            *(uint2*)(Pw + c * 128 + ((j * 32 + g * 8) ^ cswz)) = pk2;
        }

        __builtin_amdgcn_s_setprio(1);
        #pragma unroll
        for (int kk = 0; kk < 2; kk++) {
            bf16x8 pa = *(const bf16x8*)(Pw + c * 128 + ((kk * 64 + g * 16) ^ cswz));
            #pragma unroll
            for (int j = 0; j < 4; j++) {
                int vr = j * 16 + c;
                bf16x8 bv = *(const bf16x8*)(Vt + vr * 64 + (((kk * 4 + g) ^ (vr & 7)) << 3));
                o[j] = __builtin_amdgcn_mfma_f32_16x16x32_bf16(pa, bv, o[j], 0, 0, 0);
            }
        }
        __builtin_amdgcn_s_setprio(0);
    }

    l_run += __shfl_xor(l_run, 16);
    l_run += __shfl_xor(l_run, 32);

    float invr[4];
    #pragma unroll
    for (int r = 0; r < 4; r++) invr[r] = 1.f / __shfl(l_run, (g << 4) + 4 * g + r);
    #pragma unroll
    for (int r = 0; r < 4; r++) {
        size_t row = (size_t)(b * NTOK + q0 + w * 16 + 4 * g + r) * DMODEL + h * HDIM;
        #pragma unroll
        for (int j = 0; j < 4; j++)
            ctx[row + j * 16 + c] = f2bf(o[j][r] * invr[r]);
    }
}

// ---------------- launch ----------------

extern "C" void kernel_launch(void* const* d_in, const int* in_sizes, int n_in,
                              void* d_out, int out_size, void* d_ws, size_t ws_size,
                              hipStream_t stream) {
    const float* t    = (const float*)d_in[0];
    const float* x    = (const float*)d_in[1];
    const float* mask = (const float*)d_in[2];
    const float* pe   = (const float*)d_in[3];
    const float* tw1  = (const float*)d_in[4];
    const float* tb1  = (const float*)d_in[5];
    const float* tw2  = (const float*)d_in[6];
    const float* tb2  = (const float*)d_in[7];
    const float* Wq   = (const float*)d_in[8];
    const float* bq   = (const float*)d_in[9];
    const float* Wk   = (const float*)d_in[10];
    const float* bk   = (const float*)d_in[11];
    const float* Wv   = (const float*)d_in[12];
    const float* bv   = (const float*)d_in[13];
    const float* W1   = (const float*)d_in[14];
    const float* b1   = (const float*)d_in[15];
    const float* W2   = (const float*)d_in[16];
    const float* b2   = (const float*)d_in[17];
    const float* Wada = (const float*)d_in[18];
    const float* bada = (const float*)d_in[19];
    float* out = (float*)d_out;

    const bool hoist = ws_size >= 113129472ull;
    const int WL = hoist ? NLAYER : 1;

    float* z      = (float*)d_ws;
    ushort_t* cxb = (ushort_t*)(z + (size_t)ROWS * DMODEL);       // partial0 / ctx (8.4MB)
    ushort_t* cxb2 = cxb + (size_t)ROWS * DMODEL;                 // partial1 (8.4MB)
    ushort_t* qkv = cxb2 + (size_t)ROWS * DMODEL;
    ushort_t* mid = qkv;
    ushort_t* hb  = qkv + (size_t)ROWS * 2048;
    ushort_t* wqkv_t = hb + (size_t)ROWS * DMODEL;
    ushort_t* w1_t   = wqkv_t + (size_t)WL * QKVSTR * 512;
    ushort_t* w2_t   = w1_t + (size_t)WL * 2048 * 512;
    float* bqkv  = (float*)(w2_t + (size_t)WL * 512 * 2048);
    float* fzero = bqkv + NLAYER * QKVSTR;   // kept in layout (unused)
    float* temb  = fzero + 512;
    float* cmid  = temb + BATCH * 256;
    float* scs   = cmid + BATCH * DMODEL;
    float* part  = scs + BATCH * DMODEL;
    float* ada_all = part + 4 * 8 * (NLAYER * 3072);

    init_z_kernel<<<ROWS * DMODEL / 4 / 256, 256, 0, stream>>>(x, pe, z);
    temb_kernel<<<BATCH, 128, 0, stream>>>(t, temb);
    pack_bias<<<(NLAYER * QKVSTR + 255) / 256, 256, 0, stream>>>(bq, bk, bv, bqkv);

    skinny_part<<<dim3(2, 2, 1), 256, 0, stream>>>(temb, tw1, part, 256, 512, 512);
    skinny_reduce<1><<<16, 256, 0, stream>>>(part, tb1, cmid, 2, 512, 512);
    skinny_part<<<dim3(2, 4, 1), 256, 0, stream>>>(cmid, tw2, part, 512, 512, 512);
    skinny_reduce<1><<<16, 256, 0, stream>>>(part, tb2, scs, 4, 512, 512);
    skinny_part<<<dim3(12, 4, NLAYER), 256, 0, stream>>>(scs, Wada, part, 512, 3072, NLAYER * 3072);
    skinny_reduce<0><<<(8 * NLAYER * 3072 + 255) / 256, 256, 0, stream>>>(
        part, bada, ada_all, 4, 3072, NLAYER * 3072);

    if (hoist) {
        transp_all<<<dim3(2816, 1, NLAYER), 256, 0, stream>>>(Wq, Wk, Wv, W1, W2,
                                                              wqkv_t, w1_t, w2_t);
    }

    dim3 gqkv(ROWS / 128, QKVSTR / 128);
    dim3 gmlp1(ROWS / 128, 2048 / 128);
    dim3 gmlp2(ROWS / 128, DMODEL / 128, 2);   // split-K=2
    dim3 ga(BATCH * NHEAD, NTOK / 128);

    ln_mod_kernel<<<ROWS / 4, 256, 0, stream>>>(z, ada_all, hb, 0, 512);

    for (int i = 0; i < NLAYER; i++) {
        const float* ada = ada_all + (size_t)i * 8 * 3072;

        const ushort_t* wq_i = hoist ? wqkv_t + (size_t)i * QKVSTR * 512 : wqkv_t;
        const ushort_t* w1_i = hoist ? w1_t + (size_t)i * 2048 * 512 : w1_t;
        const ushort_t* w2_i = hoist ? w2_t + (size_t)i * 512 * 2048 : w2_t;

        if (!hoist) {
            transp_all<<<dim3(2816, 1, 1), 256, 0, stream>>>(Wq + (size_t)i * 512 * 512,
                                                             Wk + (size_t)i * 512 * 512,
                                                             Wv + (size_t)i * 512 * 512,
                                                             W1 + (size_t)i * 512 * 2048,
                                                             W2 + (size_t)i * 2048 * 512,
                                                             wqkv_t, w1_t, w2_t);
        }

        mfma_gemm<0, 1, 1, 0, 0><<<gqkv, 256, 0, stream>>>(hb, wq_i, bqkv + i * QKVSTR, qkv,
                                                           ROWS, QKVSTR, DMODEL);

        flash_attn_mfma<<<ga, 512, 0, stream>>>(qkv, mask, cxb);

        resid_ln_kernel<0><<<ROWS / 4, 256, 0, stream>>>(z, cxb, nullptr, nullptr,
                                                         ada, 2 * DMODEL,
                                                         ada, 3 * DMODEL, 4 * DMODEL, hb);

        mfma_gemm<1, 1, 0, 0, 0><<<gmlp1, 256, 0, stream>>>(hb, w1_i, b1 + (size_t)i * 4 * DMODEL, mid,
                                                            ROWS, 4 * DMODEL, DMODEL);
        mfma_gemm<0, 1, 0, 1, 1><<<gmlp2, 256, 0, stream>>>(mid, w2_i, nullptr, cxb,
                                                            ROWS, DMODEL, 4 * DMODEL);

        if (i < NLAYER - 1) {
            const float* adan = ada_all + (size_t)(i + 1) * 8 * 3072;
            resid_ln_kernel<1><<<ROWS / 4, 256, 0, stream>>>(z, cxb, cxb2, b2 + (size_t)i * DMODEL,
                                                             ada, 5 * DMODEL,
                                                             adan, 0, 512, hb);
        } else {
            resid_final_kernel<<<ROWS / 4, 256, 0, stream>>>(z, cxb, cxb2, b2 + (size_t)i * DMODEL,
                                                             ada, 5 * DMODEL, mask, out);
        }
    }
}